// Round 1
// baseline (3241.524 us; speedup 1.0000x reference)
//
#include <hip/hip_runtime.h>
#include <math.h>

#define R_    8192
#define D_    128
#define RD    (R_ * D_)
#define NXg   160
#define NYg   160
#define NZg   128
#define CSg   (NXg * NYg * NZg)
#define WIDm  128
#define DIM0  39
#define K0C   12
#define LAMc  0.01f
#define VSRc  2.0f

// ---------------- K0: transpose w0 (39x128) -> w0t (128x39) ----------------
__global__ void k_transpose_w0(const float* __restrict__ w0, float* __restrict__ w0t) {
    int idx = blockIdx.x * 256 + threadIdx.x;
    if (idx >= WIDm * DIM0) return;
    int k = idx / DIM0;   // hidden unit
    int m = idx % DIM0;   // input dim
    w0t[idx] = w0[m * WIDm + k];
}

// ---------------- K1: fused gather + density + alpha + MLP ----------------
__global__ __launch_bounds__(256, 2) void k_fused(
    const float* __restrict__ rays_o, const float* __restrict__ rays_d,
    const float* __restrict__ dg,  const float* __restrict__ pg,
    const float* __restrict__ kg,
    const float* __restrict__ gfd, const float* __restrict__ gfr,
    const float* __restrict__ w0t, const float* __restrict__ b0,
    const float* __restrict__ w1,  const float* __restrict__ b1,
    const float* __restrict__ w2,  const float* __restrict__ b2,
    const float* __restrict__ act_shift,
    float* __restrict__ alpha_ws, float* __restrict__ rgb_ws)
{
    int sid = blockIdx.x * 256 + threadIdx.x;
    if (sid >= RD) return;
    int r = sid >> 7;
    int s = sid & 127;

    float t = s * (1.0f / 127.0f);
    float o0 = rays_o[r * 3 + 0], o1 = rays_o[r * 3 + 1], o2 = rays_o[r * 3 + 2];
    float d0 = rays_d[r * 3 + 0], d1 = rays_d[r * 3 + 1], d2 = rays_d[r * 3 + 2];

    float px = fminf(fmaxf(o0 + d0 * t, 0.0f), 1.0f);
    float py = fminf(fmaxf(o1 + d1 * t, 0.0f), 1.0f);
    float pz = fminf(fmaxf(o2 + d2 * t, 0.0f), 1.0f);

    float gx = px * (float)(NXg - 1);
    float gy = py * (float)(NYg - 1);
    float gz = pz * (float)(NZg - 1);
    int ix = min((int)gx, NXg - 2);
    int iy = min((int)gy, NYg - 2);
    int iz = min((int)gz, NZg - 2);
    float fx = gx - (float)ix;
    float fy = gy - (float)iy;
    float fz = gz - (float)iz;

    int base = (ix * NYg + iy) * NZg + iz;
    int off[4];
    off[0] = base;                    // dx=0 dy=0
    off[1] = base + NZg;              // dx=0 dy=1
    off[2] = base + NYg * NZg;        // dx=1 dy=0
    off[3] = base + NYg * NZg + NZg;  // dx=1 dy=1
    float wxy[4];
    wxy[0] = (1.0f - fx) * (1.0f - fy);
    wxy[1] = (1.0f - fx) * fy;
    wxy[2] = fx * (1.0f - fy);
    wxy[3] = fx * fy;
    float wz0 = 1.0f - fz, wz1 = fz;

    auto tri = [&](const float* __restrict__ g, int c) -> float {
        float acc = 0.0f;
        const float* gc = g + (size_t)c * CSg;
#pragma unroll
        for (int q = 0; q < 4; ++q) {
            const float* p = gc + off[q];
            acc += (p[0] * wz0 + p[1] * wz1) * wxy[q];
        }
        return acc;
    };

    float den_v = tri(dg, 0);
    float par[16];
#pragma unroll
    for (int c = 0; c < 16; ++c) par[c] = tri(pg, c);
    float k0v[K0C];
#pragma unroll
    for (int c = 0; c < K0C; ++c) k0v[c] = tri(kg, c);

    // density activation chain
    float z = den_v + gfd[0] * LAMc;
#pragma unroll
    for (int i = 0; i < 4; ++i) {
        float pa = par[4 * i + 0], pb = par[4 * i + 1];
        float pc = par[4 * i + 2], pd = par[4 * i + 3];
        float sg = 1.0f / (1.0f + expf(-pd));
        z += pa * tanhf(pb * z + pc) * sg;
    }
    float den = z + act_shift[s];
    float sp = fmaxf(den, 0.0f) + log1pf(expf(-fabsf(den)));
    float alpha = 1.0f - expf(-sp * VSRc);
    alpha_ws[sid] = alpha;

    // view-dir embedding
    float nrm = sqrtf(d0 * d0 + d1 * d1 + d2 * d2) + 1e-8f;
    float v0 = d0 / nrm, v1 = d1 / nrm, v2 = d2 / nrm;
    float x[DIM0];
    x[0] = v0; x[1] = v1; x[2] = v2;
    float vd[3] = {v0, v1, v2};
#pragma unroll
    for (int c = 0; c < 3; ++c) {
#pragma unroll
        for (int f = 0; f < 4; ++f) {
            float ang = vd[c] * (float)(1 << f);
            x[3 + c * 4 + f]  = sinf(ang);
            x[15 + c * 4 + f] = cosf(ang);
        }
    }
#pragma unroll
    for (int c = 0; c < K0C; ++c) x[27 + c] = k0v[c];

    // MLP: layer0+layer1 fused; h1 accumulators in registers
    float h1[WIDm];
#pragma unroll
    for (int j = 0; j < WIDm; ++j) h1[j] = b1[j];

    for (int k = 0; k < WIDm; ++k) {
        float h0k = b0[k];
        const float* w0row = w0t + k * DIM0;
#pragma unroll
        for (int m = 0; m < DIM0; ++m) h0k = fmaf(x[m], w0row[m], h0k);
        h0k = fmaxf(h0k, 0.0f);
        const float* w1row = w1 + k * WIDm;
#pragma unroll
        for (int j = 0; j < WIDm; ++j) h1[j] = fmaf(h0k, w1row[j], h1[j]);
    }

    float a0 = b2[0] + gfr[0] * LAMc;
    float a1 = b2[1] + gfr[1] * LAMc;
    float a2 = b2[2] + gfr[2] * LAMc;
#pragma unroll
    for (int j = 0; j < WIDm; ++j) {
        float hj = fmaxf(h1[j], 0.0f);
        a0 = fmaf(hj, w2[j * 78 + 0], a0);
        a1 = fmaf(hj, w2[j * 78 + 1], a1);
        a2 = fmaf(hj, w2[j * 78 + 2], a2);
    }
    float rgb0 = 1.0f / (1.0f + expf(-a0));
    float rgb1 = 1.0f / (1.0f + expf(-a1));
    float rgb2 = 1.0f / (1.0f + expf(-a2));

    rgb_ws[0 * RD + sid] = rgb0;
    rgb_ws[1 * RD + sid] = rgb1;
    rgb_ws[2 * RD + sid] = rgb2;
}

// ---------------- K2: per-ray transmittance scan + weighted RGB reduce ----------------
__global__ void k_scan_reduce(const float* __restrict__ alpha_ws,
                              const float* __restrict__ rgb_ws,
                              float* __restrict__ out)
{
    int gtid = blockIdx.x * 256 + threadIdx.x;
    int r = gtid >> 6;
    int lane = gtid & 63;
    if (r >= R_) return;

    int base = r * D_ + lane * 2;
    float a0 = alpha_ws[base];
    float a1 = alpha_ws[base + 1];
    float q0 = 1.0f - a0 + 1e-10f;
    float q1 = 1.0f - a1 + 1e-10f;
    float p = q0 * q1;

    // inclusive multiplicative scan over 64 lanes
    float incl = p;
#pragma unroll
    for (int o = 1; o < 64; o <<= 1) {
        float v = __shfl_up(incl, o);
        if (lane >= o) incl *= v;
    }
    float excl = __shfl_up(incl, 1);
    if (lane == 0) excl = 1.0f;
    float Tlast = __shfl(incl, 63);

    float w0s = a0 * excl;          // T_excl for sample 2*lane
    float w1s = a1 * excl * q0;     // T_excl for sample 2*lane+1

    float sums[3];
#pragma unroll
    for (int c = 0; c < 3; ++c) {
        float rg0 = rgb_ws[c * RD + base];
        float rg1 = rgb_ws[c * RD + base + 1];
        float sc = w0s * rg0 + w1s * rg1;
#pragma unroll
        for (int o = 32; o >= 1; o >>= 1) sc += __shfl_xor(sc, o);
        sums[c] = sc;
    }
    if (lane == 0) {
#pragma unroll
        for (int c = 0; c < 3; ++c) out[r * 3 + c] = sums[c] + Tlast;
    }
}

extern "C" void kernel_launch(void* const* d_in, const int* in_sizes, int n_in,
                              void* d_out, int out_size, void* d_ws, size_t ws_size,
                              hipStream_t stream) {
    const float* rays_o    = (const float*)d_in[0];
    const float* rays_d    = (const float*)d_in[1];
    const float* dg        = (const float*)d_in[2];
    const float* pg        = (const float*)d_in[3];
    const float* kg        = (const float*)d_in[4];
    const float* gfd       = (const float*)d_in[5];
    const float* gfr       = (const float*)d_in[6];
    const float* w0        = (const float*)d_in[7];
    const float* b0        = (const float*)d_in[8];
    const float* w1        = (const float*)d_in[9];
    const float* b1        = (const float*)d_in[10];
    const float* w2        = (const float*)d_in[11];
    const float* b2        = (const float*)d_in[12];
    const float* act_shift = (const float*)d_in[13];
    float* out = (float*)d_out;

    float* ws = (float*)d_ws;
    float* alpha_ws = ws;            // RD floats
    float* rgb_ws   = ws + RD;       // 3*RD floats
    float* w0t_ws   = ws + 4 * RD;   // 128*39 floats

    k_transpose_w0<<<dim3((WIDm * DIM0 + 255) / 256), dim3(256), 0, stream>>>(w0, w0t_ws);
    k_fused<<<dim3(RD / 256), dim3(256), 0, stream>>>(
        rays_o, rays_d, dg, pg, kg, gfd, gfr,
        w0t_ws, b0, w1, b1, w2, b2, act_shift,
        alpha_ws, rgb_ws);
    k_scan_reduce<<<dim3(R_ / 4), dim3(256), 0, stream>>>(alpha_ws, rgb_ws, out);
}

// Round 2
// 1241.127 us; speedup vs baseline: 2.6118x; 2.6118x over previous
//
#include <hip/hip_runtime.h>
#include <math.h>

#define R_    8192
#define D_    128
#define RD    (R_ * D_)
#define NXg   160
#define NYg   160
#define NZg   128
#define CSg   (NXg * NYg * NZg)
#define WIDm  128
#define K0C   12
#define LAMc  0.01f
#define VSRc  2.0f

typedef __attribute__((ext_vector_type(8))) short   short8v;
typedef __attribute__((ext_vector_type(4))) float   f32x4;
typedef __attribute__((ext_vector_type(4))) unsigned short ushort4v;
typedef __attribute__((ext_vector_type(8))) unsigned short ushort8v;

static __device__ __forceinline__ unsigned short f2b(float f) {
    union { float f; unsigned int u; } v; v.f = f;
    unsigned int r = v.u + 0x7fffu + ((v.u >> 16) & 1u);   // RNE
    return (unsigned short)(r >> 16);
}

// ---------------- prep A: per-ray embedding partial e[r][128] = emb@w0[0:27] + b0 ----
__global__ void k_prep_e(const float* __restrict__ rays_d,
                         const float* __restrict__ w0, const float* __restrict__ b0,
                         float* __restrict__ e) {
    int r = blockIdx.x;
    int j = threadIdx.x;
    float d0 = rays_d[r * 3 + 0], d1 = rays_d[r * 3 + 1], d2 = rays_d[r * 3 + 2];
    float nrm = sqrtf(d0 * d0 + d1 * d1 + d2 * d2) + 1e-8f;
    float v[3] = { d0 / nrm, d1 / nrm, d2 / nrm };
    float x[27];
    x[0] = v[0]; x[1] = v[1]; x[2] = v[2];
#pragma unroll
    for (int c = 0; c < 3; ++c)
#pragma unroll
        for (int f = 0; f < 4; ++f) {
            float ang = v[c] * (float)(1 << f);
            x[3 + c * 4 + f]  = sinf(ang);
            x[15 + c * 4 + f] = cosf(ang);
        }
    float acc = b0[j];
#pragma unroll
    for (int m = 0; m < 27; ++m) acc = fmaf(x[m], w0[m * WIDm + j], acc);
    e[r * WIDm + j] = acc;
}

// ---------------- prep B: pre-fragment weights into MFMA A-fragment order (bf16) ----
// A-frag mapping (16x16x32): lane l holds row m=(l&15), k = kc*32 + 8*(l>>4) + j, j=0..7
__global__ void k_prep_frags(const float* __restrict__ w0, const float* __restrict__ w1,
                             const float* __restrict__ w2,
                             unsigned short* __restrict__ w1f,
                             unsigned short* __restrict__ w0kf,
                             unsigned short* __restrict__ w2f) {
    int t = blockIdx.x * 256 + threadIdx.x;
    if (t < 16384) {                       // w1^T frags: 8 mt x 4 kc tiles
        int tile = t >> 9, lane = (t >> 3) & 63, j = t & 7;
        int mt = tile >> 2, kc = tile & 3;
        int k = kc * 32 + 8 * (lane >> 4) + j;
        int m = mt * 16 + (lane & 15);
        w1f[t] = f2b(w1[k * WIDm + m]);
    } else if (t < 16384 + 4096) {         // w0[27:39]^T frags: 8 mt tiles, K=32 (pad>=12 -> 0)
        int u = t - 16384;
        int mt = u >> 9, lane = (u >> 3) & 63, j = u & 7;
        int k = 8 * (lane >> 4) + j;
        int m = mt * 16 + (lane & 15);
        w0kf[u] = f2b(k < K0C ? w0[(27 + k) * WIDm + m] : 0.0f);
    } else if (t < 16384 + 4096 + 2048) {  // w2[:, 0:3]^T frags: 1 mt x 4 kc, rows>=3 -> 0
        int u = t - 16384 - 4096;
        int kc = u >> 9, lane = (u >> 3) & 63, j = u & 7;
        int k = kc * 32 + 8 * (lane >> 4) + j;
        int m = lane & 15;
        w2f[u] = f2b(m < 3 ? w2[k * 78 + m] : 0.0f);
    }
}

// ---------------- K1: gather + density chain + alpha + k0 features (bf16) ----------
__global__ void k_gather(
    const float* __restrict__ rays_o, const float* __restrict__ rays_d,
    const float* __restrict__ dg,  const float* __restrict__ pg,
    const float* __restrict__ kg,  const float* __restrict__ gfd,
    const float* __restrict__ act_shift,
    float* __restrict__ alpha_ws, unsigned short* __restrict__ k0b)
{
    int sid = blockIdx.x * 256 + threadIdx.x;
    if (sid >= RD) return;
    int r = sid >> 7;
    int s = sid & 127;

    float t = s * (1.0f / 127.0f);
    float o0 = rays_o[r * 3 + 0], o1 = rays_o[r * 3 + 1], o2 = rays_o[r * 3 + 2];
    float d0 = rays_d[r * 3 + 0], d1 = rays_d[r * 3 + 1], d2 = rays_d[r * 3 + 2];

    float px = fminf(fmaxf(o0 + d0 * t, 0.0f), 1.0f);
    float py = fminf(fmaxf(o1 + d1 * t, 0.0f), 1.0f);
    float pz = fminf(fmaxf(o2 + d2 * t, 0.0f), 1.0f);

    float gx = px * (float)(NXg - 1);
    float gy = py * (float)(NYg - 1);
    float gz = pz * (float)(NZg - 1);
    int ix = min((int)gx, NXg - 2);
    int iy = min((int)gy, NYg - 2);
    int iz = min((int)gz, NZg - 2);
    float fx = gx - (float)ix;
    float fy = gy - (float)iy;
    float fz = gz - (float)iz;

    int base = (ix * NYg + iy) * NZg + iz;
    int off[4];
    off[0] = base;
    off[1] = base + NZg;
    off[2] = base + NYg * NZg;
    off[3] = base + NYg * NZg + NZg;
    float wxy[4];
    wxy[0] = (1.0f - fx) * (1.0f - fy);
    wxy[1] = (1.0f - fx) * fy;
    wxy[2] = fx * (1.0f - fy);
    wxy[3] = fx * fy;
    float wz0 = 1.0f - fz, wz1 = fz;

    auto tri = [&](const float* __restrict__ g, int c) -> float {
        float acc = 0.0f;
        const float* gc = g + (size_t)c * CSg;
#pragma unroll
        for (int q = 0; q < 4; ++q) {
            const float* p = gc + off[q];
            acc += (p[0] * wz0 + p[1] * wz1) * wxy[q];
        }
        return acc;
    };

    float den_v = tri(dg, 0);
    float par[16];
#pragma unroll
    for (int c = 0; c < 16; ++c) par[c] = tri(pg, c);
    float k0v[K0C];
#pragma unroll
    for (int c = 0; c < K0C; ++c) k0v[c] = tri(kg, c);

    float z = den_v + gfd[0] * LAMc;
#pragma unroll
    for (int i = 0; i < 4; ++i) {
        float pa = par[4 * i + 0], pb = par[4 * i + 1];
        float pc = par[4 * i + 2], pd = par[4 * i + 3];
        float sg = 1.0f / (1.0f + expf(-pd));
        z += pa * tanhf(pb * z + pc) * sg;
    }
    float den = z + act_shift[s];
    float sp = fmaxf(den, 0.0f) + log1pf(expf(-fabsf(den)));
    alpha_ws[sid] = 1.0f - expf(-sp * VSRc);

    // k0 features, bf16, padded to 16 (two 16B coalesced stores)
    ushort8v lo, hi;
#pragma unroll
    for (int c = 0; c < 8; ++c) lo[c] = f2b(k0v[c]);
#pragma unroll
    for (int c = 0; c < 8; ++c) hi[c] = (c < 4) ? f2b(k0v[8 + c]) : (unsigned short)0;
    *(ushort8v*)(k0b + (size_t)sid * 16)     = lo;
    *(ushort8v*)(k0b + (size_t)sid * 16 + 8) = hi;
}

// ---------------- K2: MFMA MLP. wave = 16 samples (one ray), M=hidden, N=samples ----
__global__ __launch_bounds__(256) void k_mlp(
    const unsigned short* __restrict__ k0b, const float* __restrict__ e,
    const unsigned short* __restrict__ w0kf, const unsigned short* __restrict__ w1f,
    const unsigned short* __restrict__ w2f,
    const float* __restrict__ b1, const float* __restrict__ b2,
    const float* __restrict__ gfr,
    float* __restrict__ rgb_ws)
{
    __shared__ unsigned short h0_lds[4][16][136];   // pitch 272B: 16B aligned rows
    __shared__ unsigned short h1_lds[4][16][136];
    const int wid  = threadIdx.x >> 6;
    const int lane = threadIdx.x & 63;
    const int g    = lane >> 4;
    const int scol = lane & 15;
    const int sbase = blockIdx.x * 64 + wid * 16;
    const int ray   = sbase >> 7;                   // uniform across the wave's 16 samples

    const f32x4 zero4 = { 0.0f, 0.0f, 0.0f, 0.0f };

    // ---- layer 0: h0[128][16] = w0k^T (128x32) @ k0feat (32x16) ----
    short8v bf0 = { 0,0,0,0,0,0,0,0 };
    if (g < 2)
        bf0 = *(const short8v*)(k0b + ((size_t)(sbase + scol)) * 16 + g * 8);

    f32x4 acc0[8];
#pragma unroll
    for (int mt = 0; mt < 8; ++mt) {
        short8v af = *(const short8v*)(w0kf + (mt * 64 + lane) * 8);
        acc0[mt] = __builtin_amdgcn_mfma_f32_16x16x32_bf16(af, bf0, zero4, 0, 0, 0);
    }
    // epilogue: + e[ray][m], relu, bf16 -> LDS [sample][hidden]
#pragma unroll
    for (int mt = 0; mt < 8; ++mt) {
        f32x4 ev = *(const f32x4*)(e + ray * WIDm + mt * 16 + 4 * g);
        ushort4v pk;
#pragma unroll
        for (int i = 0; i < 4; ++i) {
            float v = acc0[mt][i] + ev[i];
            pk[i] = f2b(fmaxf(v, 0.0f));
        }
        *(ushort4v*)&h0_lds[wid][scol][mt * 16 + 4 * g] = pk;
    }
    __syncthreads();

    // ---- layer 1: h1[128][16] = w1^T (128x128) @ h0 (128x16) ----
    short8v bfr[4];
#pragma unroll
    for (int kc = 0; kc < 4; ++kc)
        bfr[kc] = *(const short8v*)&h0_lds[wid][scol][kc * 32 + 8 * g];

    f32x4 acc1[8];
#pragma unroll
    for (int mt = 0; mt < 8; ++mt) acc1[mt] = zero4;
#pragma unroll
    for (int mt = 0; mt < 8; ++mt)
#pragma unroll
        for (int kc = 0; kc < 4; ++kc) {
            short8v af = *(const short8v*)(w1f + ((mt * 4 + kc) * 64 + lane) * 8);
            acc1[mt] = __builtin_amdgcn_mfma_f32_16x16x32_bf16(af, bfr[kc], acc1[mt], 0, 0, 0);
        }
    // epilogue: + b1, relu, bf16 -> LDS
#pragma unroll
    for (int mt = 0; mt < 8; ++mt) {
        f32x4 bv = *(const f32x4*)(b1 + mt * 16 + 4 * g);
        ushort4v pk;
#pragma unroll
        for (int i = 0; i < 4; ++i) {
            float v = acc1[mt][i] + bv[i];
            pk[i] = f2b(fmaxf(v, 0.0f));
        }
        *(ushort4v*)&h1_lds[wid][scol][mt * 16 + 4 * g] = pk;
    }
    __syncthreads();

    // ---- layer 2: rgb[3][16] = w2pad^T (16x128) @ h1 (128x16) ----
    short8v cfr[4];
#pragma unroll
    for (int kc = 0; kc < 4; ++kc)
        cfr[kc] = *(const short8v*)&h1_lds[wid][scol][kc * 32 + 8 * g];

    f32x4 acc2 = zero4;
#pragma unroll
    for (int kc = 0; kc < 4; ++kc) {
        short8v af = *(const short8v*)(w2f + (kc * 64 + lane) * 8);
        acc2 = __builtin_amdgcn_mfma_f32_16x16x32_bf16(af, cfr[kc], acc2, 0, 0, 0);
    }
    if (lane < 16) {
        int sid = sbase + lane;
#pragma unroll
        for (int c = 0; c < 3; ++c) {
            float v = acc2[c] + b2[c] + gfr[c] * LAMc;
            rgb_ws[(size_t)c * RD + sid] = 1.0f / (1.0f + expf(-v));
        }
    }
}

// ---------------- K3: per-ray transmittance scan + weighted RGB reduce -------------
__global__ void k_scan_reduce(const float* __restrict__ alpha_ws,
                              const float* __restrict__ rgb_ws,
                              float* __restrict__ out)
{
    int gtid = blockIdx.x * 256 + threadIdx.x;
    int r = gtid >> 6;
    int lane = gtid & 63;
    if (r >= R_) return;

    int base = r * D_ + lane * 2;
    float a0 = alpha_ws[base];
    float a1 = alpha_ws[base + 1];
    float q0 = 1.0f - a0 + 1e-10f;
    float q1 = 1.0f - a1 + 1e-10f;
    float p = q0 * q1;

    float incl = p;
#pragma unroll
    for (int o = 1; o < 64; o <<= 1) {
        float v = __shfl_up(incl, o);
        if (lane >= o) incl *= v;
    }
    float excl = __shfl_up(incl, 1);
    if (lane == 0) excl = 1.0f;
    float Tlast = __shfl(incl, 63);

    float w0s = a0 * excl;
    float w1s = a1 * excl * q0;

    float sums[3];
#pragma unroll
    for (int c = 0; c < 3; ++c) {
        float rg0 = rgb_ws[(size_t)c * RD + base];
        float rg1 = rgb_ws[(size_t)c * RD + base + 1];
        float sc = w0s * rg0 + w1s * rg1;
#pragma unroll
        for (int o = 32; o >= 1; o >>= 1) sc += __shfl_xor(sc, o);
        sums[c] = sc;
    }
    if (lane == 0) {
#pragma unroll
        for (int c = 0; c < 3; ++c) out[r * 3 + c] = sums[c] + Tlast;
    }
}

extern "C" void kernel_launch(void* const* d_in, const int* in_sizes, int n_in,
                              void* d_out, int out_size, void* d_ws, size_t ws_size,
                              hipStream_t stream) {
    const float* rays_o    = (const float*)d_in[0];
    const float* rays_d    = (const float*)d_in[1];
    const float* dg        = (const float*)d_in[2];
    const float* pg        = (const float*)d_in[3];
    const float* kg        = (const float*)d_in[4];
    const float* gfd       = (const float*)d_in[5];
    const float* gfr       = (const float*)d_in[6];
    const float* w0        = (const float*)d_in[7];
    const float* b0        = (const float*)d_in[8];
    const float* w1        = (const float*)d_in[9];
    const float* b1        = (const float*)d_in[10];
    const float* w2        = (const float*)d_in[11];
    const float* b2        = (const float*)d_in[12];
    const float* act_shift = (const float*)d_in[13];
    float* out = (float*)d_out;

    float* ws = (float*)d_ws;
    float*          alpha_ws = ws;                               // RD f32
    float*          rgb_ws   = ws + (size_t)RD;                  // 3*RD f32
    unsigned short* k0b      = (unsigned short*)(ws + 4 * (size_t)RD);   // RD*16 u16 (=8RD f32)
    float*          e_ws     = ws + 12 * (size_t)RD;             // RD f32 (8192*128)
    unsigned short* w1f      = (unsigned short*)(ws + 13 * (size_t)RD);  // 16384 u16
    unsigned short* w0kf     = w1f + 16384;                      // 4096 u16
    unsigned short* w2f      = w0kf + 4096;                      // 2048 u16

    k_prep_e<<<dim3(R_), dim3(WIDm), 0, stream>>>(rays_d, w0, b0, e_ws);
    k_prep_frags<<<dim3(88), dim3(256), 0, stream>>>(w0, w1, w2, w1f, w0kf, w2f);
    k_gather<<<dim3(RD / 256), dim3(256), 0, stream>>>(
        rays_o, rays_d, dg, pg, kg, gfd, act_shift, alpha_ws, k0b);
    k_mlp<<<dim3(RD / 64), dim3(256), 0, stream>>>(
        k0b, e_ws, w0kf, w1f, w2f, b1, b2, gfr, rgb_ws);
    k_scan_reduce<<<dim3(R_ / 4), dim3(256), 0, stream>>>(alpha_ws, rgb_ws, out);
}

// Round 3
// 349.841 us; speedup vs baseline: 9.2657x; 3.5477x over previous
//
#include <hip/hip_runtime.h>
#include <math.h>

#define R_    8192
#define D_    128
#define RD    (R_ * D_)
#define NXg   160
#define NYg   160
#define NZg   128
#define CSg   (NXg * NYg * NZg)
#define WIDm  128
#define K0C   12
#define LAMc  0.01f
#define VSRc  2.0f

typedef __attribute__((ext_vector_type(8))) short   short8v;
typedef __attribute__((ext_vector_type(4))) float   f32x4;
typedef __attribute__((ext_vector_type(4))) unsigned short ushort4v;
typedef __attribute__((ext_vector_type(8))) unsigned short ushort8v;

static __device__ __forceinline__ unsigned short f2b(float f) {
    union { float f; unsigned int u; } v; v.f = f;
    unsigned int r = v.u + 0x7fffu + ((v.u >> 16) & 1u);   // RNE
    return (unsigned short)(r >> 16);
}
static __device__ __forceinline__ float b2f(unsigned short u) {
    union { unsigned int u; float f; } v; v.u = ((unsigned int)u) << 16;
    return v.f;
}

// ---------------- pack: 29 channel planes -> voxel-major AoS bf16 (64 B/voxel) -----
__global__ void k_pack_vox(const float* __restrict__ dg, const float* __restrict__ pg,
                           const float* __restrict__ kg, unsigned short* __restrict__ vox) {
    int v = blockIdx.x * 256 + threadIdx.x;
    if (v >= CSg) return;
    unsigned short rec[32];
    rec[0] = f2b(dg[v]);
#pragma unroll
    for (int c = 0; c < 16; ++c) rec[1 + c]  = f2b(pg[(size_t)c * CSg + v]);
#pragma unroll
    for (int c = 0; c < K0C; ++c) rec[17 + c] = f2b(kg[(size_t)c * CSg + v]);
    rec[29] = 0; rec[30] = 0; rec[31] = 0;
    unsigned short* dst = vox + (size_t)v * 32;
#pragma unroll
    for (int i = 0; i < 4; ++i)
        *(ushort8v*)(dst + i * 8) = *(ushort8v*)(rec + i * 8);
}

// ---------------- prep A: per-ray embedding partial e[r][128] = emb@w0[0:27] + b0 ----
__global__ void k_prep_e(const float* __restrict__ rays_d,
                         const float* __restrict__ w0, const float* __restrict__ b0,
                         float* __restrict__ e) {
    int r = blockIdx.x;
    int j = threadIdx.x;
    float d0 = rays_d[r * 3 + 0], d1 = rays_d[r * 3 + 1], d2 = rays_d[r * 3 + 2];
    float nrm = sqrtf(d0 * d0 + d1 * d1 + d2 * d2) + 1e-8f;
    float v[3] = { d0 / nrm, d1 / nrm, d2 / nrm };
    float x[27];
    x[0] = v[0]; x[1] = v[1]; x[2] = v[2];
#pragma unroll
    for (int c = 0; c < 3; ++c)
#pragma unroll
        for (int f = 0; f < 4; ++f) {
            float ang = v[c] * (float)(1 << f);
            x[3 + c * 4 + f]  = sinf(ang);
            x[15 + c * 4 + f] = cosf(ang);
        }
    float acc = b0[j];
#pragma unroll
    for (int m = 0; m < 27; ++m) acc = fmaf(x[m], w0[m * WIDm + j], acc);
    e[r * WIDm + j] = acc;
}

// ---------------- prep B: pre-fragment weights into MFMA A-fragment order (bf16) ----
__global__ void k_prep_frags(const float* __restrict__ w0, const float* __restrict__ w1,
                             const float* __restrict__ w2,
                             unsigned short* __restrict__ w1f,
                             unsigned short* __restrict__ w0kf,
                             unsigned short* __restrict__ w2f) {
    int t = blockIdx.x * 256 + threadIdx.x;
    if (t < 16384) {                       // w1^T frags: 8 mt x 4 kc tiles
        int tile = t >> 9, lane = (t >> 3) & 63, j = t & 7;
        int mt = tile >> 2, kc = tile & 3;
        int k = kc * 32 + 8 * (lane >> 4) + j;
        int m = mt * 16 + (lane & 15);
        w1f[t] = f2b(w1[k * WIDm + m]);
    } else if (t < 16384 + 4096) {         // w0[27:39]^T frags
        int u = t - 16384;
        int mt = u >> 9, lane = (u >> 3) & 63, j = u & 7;
        int k = 8 * (lane >> 4) + j;
        int m = mt * 16 + (lane & 15);
        w0kf[u] = f2b(k < K0C ? w0[(27 + k) * WIDm + m] : 0.0f);
    } else if (t < 16384 + 4096 + 2048) {  // w2[:, 0:3]^T frags
        int u = t - 16384 - 4096;
        int kc = u >> 9, lane = (u >> 3) & 63, j = u & 7;
        int k = kc * 32 + 8 * (lane >> 4) + j;
        int m = lane & 15;
        w2f[u] = f2b(m < 3 ? w2[k * 78 + m] : 0.0f);
    }
}

// =============== shared per-sample math (density chain + alpha + k0 out) ===========
static __device__ __forceinline__ void finish_sample(
    int sid, int s, const float* acc /*29*/, const float* __restrict__ gfd,
    const float* __restrict__ act_shift,
    float* __restrict__ alpha_ws, unsigned short* __restrict__ k0b)
{
    float z = acc[0] + gfd[0] * LAMc;
#pragma unroll
    for (int i = 0; i < 4; ++i) {
        float pa = acc[1 + 4 * i + 0], pb = acc[1 + 4 * i + 1];
        float pc = acc[1 + 4 * i + 2], pd = acc[1 + 4 * i + 3];
        float sg = 1.0f / (1.0f + expf(-pd));
        z += pa * tanhf(pb * z + pc) * sg;
    }
    float den = z + act_shift[s];
    float sp = fmaxf(den, 0.0f) + log1pf(expf(-fabsf(den)));
    alpha_ws[sid] = 1.0f - expf(-sp * VSRc);

    ushort8v lo, hi;
#pragma unroll
    for (int c = 0; c < 8; ++c) lo[c] = f2b(acc[17 + c]);
#pragma unroll
    for (int c = 0; c < 8; ++c) hi[c] = (c < 4) ? f2b(acc[17 + 8 + c]) : (unsigned short)0;
    *(ushort8v*)(k0b + (size_t)sid * 16)     = lo;
    *(ushort8v*)(k0b + (size_t)sid * 16 + 8) = hi;
}

static __device__ __forceinline__ void sample_coords(
    int sid, const float* __restrict__ rays_o, const float* __restrict__ rays_d,
    int& ix, int& iy, int& iz, float& fx, float& fy, float& fz)
{
    int r = sid >> 7;
    int s = sid & 127;
    float t = s * (1.0f / 127.0f);
    float px = fminf(fmaxf(rays_o[r * 3 + 0] + rays_d[r * 3 + 0] * t, 0.0f), 1.0f);
    float py = fminf(fmaxf(rays_o[r * 3 + 1] + rays_d[r * 3 + 1] * t, 0.0f), 1.0f);
    float pz = fminf(fmaxf(rays_o[r * 3 + 2] + rays_d[r * 3 + 2] * t, 0.0f), 1.0f);
    float gx = px * (float)(NXg - 1);
    float gy = py * (float)(NYg - 1);
    float gz = pz * (float)(NZg - 1);
    ix = min((int)gx, NXg - 2);
    iy = min((int)gy, NYg - 2);
    iz = min((int)gz, NZg - 2);
    fx = gx - (float)ix;
    fy = gy - (float)iy;
    fz = gz - (float)iz;
}

// ---------------- K1a: AoS gather (preferred) --------------------------------------
__global__ __launch_bounds__(256) void k_gather_aos(
    const float* __restrict__ rays_o, const float* __restrict__ rays_d,
    const unsigned short* __restrict__ vox,
    const float* __restrict__ gfd, const float* __restrict__ act_shift,
    float* __restrict__ alpha_ws, unsigned short* __restrict__ k0b)
{
    int sid = blockIdx.x * 256 + threadIdx.x;
    if (sid >= RD) return;
    int ix, iy, iz; float fx, fy, fz;
    sample_coords(sid, rays_o, rays_d, ix, iy, iz, fx, fy, fz);

    const unsigned short* base = vox + ((size_t)(ix * NYg + iy) * NZg + iz) * 32;
    const size_t qoff[4] = { 0, (size_t)NZg * 32, (size_t)NYg * NZg * 32,
                             (size_t)(NYg + 1) * NZg * 32 };
    float wxy[4];
    wxy[0] = (1.0f - fx) * (1.0f - fy);
    wxy[1] = (1.0f - fx) * fy;
    wxy[2] = fx * (1.0f - fy);
    wxy[3] = fx * fy;
    float wz0 = 1.0f - fz, wz1 = fz;

    float acc[29];
#pragma unroll
    for (int c = 0; c < 29; ++c) acc[c] = 0.0f;

#pragma unroll
    for (int q = 0; q < 4; ++q) {
        const unsigned short* p = base + qoff[q];
#pragma unroll
        for (int dz = 0; dz < 2; ++dz) {
            float w = wxy[q] * (dz ? wz1 : wz0);
            const ushort8v* pv = (const ushort8v*)(p + dz * 32);
            ushort8v v0 = pv[0], v1 = pv[1], v2 = pv[2], v3 = pv[3];
#pragma unroll
            for (int i = 0; i < 8; ++i) acc[i]      = fmaf(w, b2f(v0[i]), acc[i]);
#pragma unroll
            for (int i = 0; i < 8; ++i) acc[8 + i]  = fmaf(w, b2f(v1[i]), acc[8 + i]);
#pragma unroll
            for (int i = 0; i < 8; ++i) acc[16 + i] = fmaf(w, b2f(v2[i]), acc[16 + i]);
#pragma unroll
            for (int i = 0; i < 5; ++i) acc[24 + i] = fmaf(w, b2f(v3[i]), acc[24 + i]);
        }
    }
    finish_sample(sid, sid & 127, acc, gfd, act_shift, alpha_ws, k0b);
}

// ---------------- K1b: SoA f32 gather (fallback when ws too small) -----------------
__global__ void k_gather_soa(
    const float* __restrict__ rays_o, const float* __restrict__ rays_d,
    const float* __restrict__ dg,  const float* __restrict__ pg,
    const float* __restrict__ kg,  const float* __restrict__ gfd,
    const float* __restrict__ act_shift,
    float* __restrict__ alpha_ws, unsigned short* __restrict__ k0b)
{
    int sid = blockIdx.x * 256 + threadIdx.x;
    if (sid >= RD) return;
    int ix, iy, iz; float fx, fy, fz;
    sample_coords(sid, rays_o, rays_d, ix, iy, iz, fx, fy, fz);

    int base = (ix * NYg + iy) * NZg + iz;
    int off[4] = { base, base + NZg, base + NYg * NZg, base + NYg * NZg + NZg };
    float wxy[4];
    wxy[0] = (1.0f - fx) * (1.0f - fy);
    wxy[1] = (1.0f - fx) * fy;
    wxy[2] = fx * (1.0f - fy);
    wxy[3] = fx * fy;
    float wz0 = 1.0f - fz, wz1 = fz;

    auto tri = [&](const float* __restrict__ g, int c) -> float {
        float a = 0.0f;
        const float* gc = g + (size_t)c * CSg;
#pragma unroll
        for (int q = 0; q < 4; ++q) {
            const float* p = gc + off[q];
            a += (p[0] * wz0 + p[1] * wz1) * wxy[q];
        }
        return a;
    };
    float acc[29];
    acc[0] = tri(dg, 0);
#pragma unroll
    for (int c = 0; c < 16; ++c) acc[1 + c] = tri(pg, c);
#pragma unroll
    for (int c = 0; c < K0C; ++c) acc[17 + c] = tri(kg, c);
    finish_sample(sid, sid & 127, acc, gfd, act_shift, alpha_ws, k0b);
}

// ---------------- K2: MFMA MLP -----------------------------------------------------
__global__ __launch_bounds__(256) void k_mlp(
    const unsigned short* __restrict__ k0b, const float* __restrict__ e,
    const unsigned short* __restrict__ w0kf, const unsigned short* __restrict__ w1f,
    const unsigned short* __restrict__ w2f,
    const float* __restrict__ b1, const float* __restrict__ b2,
    const float* __restrict__ gfr,
    float* __restrict__ rgb_ws)
{
    __shared__ unsigned short h0_lds[4][16][136];
    __shared__ unsigned short h1_lds[4][16][136];
    const int wid  = threadIdx.x >> 6;
    const int lane = threadIdx.x & 63;
    const int g    = lane >> 4;
    const int scol = lane & 15;
    const int sbase = blockIdx.x * 64 + wid * 16;
    const int ray   = sbase >> 7;

    const f32x4 zero4 = { 0.0f, 0.0f, 0.0f, 0.0f };

    short8v bf0 = { 0,0,0,0,0,0,0,0 };
    if (g < 2)
        bf0 = *(const short8v*)(k0b + ((size_t)(sbase + scol)) * 16 + g * 8);

    f32x4 acc0[8];
#pragma unroll
    for (int mt = 0; mt < 8; ++mt) {
        short8v af = *(const short8v*)(w0kf + (mt * 64 + lane) * 8);
        acc0[mt] = __builtin_amdgcn_mfma_f32_16x16x32_bf16(af, bf0, zero4, 0, 0, 0);
    }
#pragma unroll
    for (int mt = 0; mt < 8; ++mt) {
        f32x4 ev = *(const f32x4*)(e + ray * WIDm + mt * 16 + 4 * g);
        ushort4v pk;
#pragma unroll
        for (int i = 0; i < 4; ++i) {
            float v = acc0[mt][i] + ev[i];
            pk[i] = f2b(fmaxf(v, 0.0f));
        }
        *(ushort4v*)&h0_lds[wid][scol][mt * 16 + 4 * g] = pk;
    }
    __syncthreads();

    short8v bfr[4];
#pragma unroll
    for (int kc = 0; kc < 4; ++kc)
        bfr[kc] = *(const short8v*)&h0_lds[wid][scol][kc * 32 + 8 * g];

    f32x4 acc1[8];
#pragma unroll
    for (int mt = 0; mt < 8; ++mt) acc1[mt] = zero4;
#pragma unroll
    for (int mt = 0; mt < 8; ++mt)
#pragma unroll
        for (int kc = 0; kc < 4; ++kc) {
            short8v af = *(const short8v*)(w1f + ((mt * 4 + kc) * 64 + lane) * 8);
            acc1[mt] = __builtin_amdgcn_mfma_f32_16x16x32_bf16(af, bfr[kc], acc1[mt], 0, 0, 0);
        }
#pragma unroll
    for (int mt = 0; mt < 8; ++mt) {
        f32x4 bv = *(const f32x4*)(b1 + mt * 16 + 4 * g);
        ushort4v pk;
#pragma unroll
        for (int i = 0; i < 4; ++i) {
            float v = acc1[mt][i] + bv[i];
            pk[i] = f2b(fmaxf(v, 0.0f));
        }
        *(ushort4v*)&h1_lds[wid][scol][mt * 16 + 4 * g] = pk;
    }
    __syncthreads();

    short8v cfr[4];
#pragma unroll
    for (int kc = 0; kc < 4; ++kc)
        cfr[kc] = *(const short8v*)&h1_lds[wid][scol][kc * 32 + 8 * g];

    f32x4 acc2 = zero4;
#pragma unroll
    for (int kc = 0; kc < 4; ++kc) {
        short8v af = *(const short8v*)(w2f + (kc * 64 + lane) * 8);
        acc2 = __builtin_amdgcn_mfma_f32_16x16x32_bf16(af, cfr[kc], acc2, 0, 0, 0);
    }
    if (lane < 16) {
        int sid = sbase + lane;
#pragma unroll
        for (int c = 0; c < 3; ++c) {
            float v = acc2[c] + b2[c] + gfr[c] * LAMc;
            rgb_ws[(size_t)c * RD + sid] = 1.0f / (1.0f + expf(-v));
        }
    }
}

// ---------------- K3: per-ray transmittance scan + weighted RGB reduce -------------
__global__ void k_scan_reduce(const float* __restrict__ alpha_ws,
                              const float* __restrict__ rgb_ws,
                              float* __restrict__ out)
{
    int gtid = blockIdx.x * 256 + threadIdx.x;
    int r = gtid >> 6;
    int lane = gtid & 63;
    if (r >= R_) return;

    int base = r * D_ + lane * 2;
    float a0 = alpha_ws[base];
    float a1 = alpha_ws[base + 1];
    float q0 = 1.0f - a0 + 1e-10f;
    float q1 = 1.0f - a1 + 1e-10f;
    float p = q0 * q1;

    float incl = p;
#pragma unroll
    for (int o = 1; o < 64; o <<= 1) {
        float v = __shfl_up(incl, o);
        if (lane >= o) incl *= v;
    }
    float excl = __shfl_up(incl, 1);
    if (lane == 0) excl = 1.0f;
    float Tlast = __shfl(incl, 63);

    float w0s = a0 * excl;
    float w1s = a1 * excl * q0;

    float sums[3];
#pragma unroll
    for (int c = 0; c < 3; ++c) {
        float rg0 = rgb_ws[(size_t)c * RD + base];
        float rg1 = rgb_ws[(size_t)c * RD + base + 1];
        float sc = w0s * rg0 + w1s * rg1;
#pragma unroll
        for (int o = 32; o >= 1; o >>= 1) sc += __shfl_xor(sc, o);
        sums[c] = sc;
    }
    if (lane == 0) {
#pragma unroll
        for (int c = 0; c < 3; ++c) out[r * 3 + c] = sums[c] + Tlast;
    }
}

extern "C" void kernel_launch(void* const* d_in, const int* in_sizes, int n_in,
                              void* d_out, int out_size, void* d_ws, size_t ws_size,
                              hipStream_t stream) {
    const float* rays_o    = (const float*)d_in[0];
    const float* rays_d    = (const float*)d_in[1];
    const float* dg        = (const float*)d_in[2];
    const float* pg        = (const float*)d_in[3];
    const float* kg        = (const float*)d_in[4];
    const float* gfd       = (const float*)d_in[5];
    const float* gfr       = (const float*)d_in[6];
    const float* w0        = (const float*)d_in[7];
    const float* b0        = (const float*)d_in[8];
    const float* w1        = (const float*)d_in[9];
    const float* b1        = (const float*)d_in[10];
    const float* w2        = (const float*)d_in[11];
    const float* b2        = (const float*)d_in[12];
    const float* act_shift = (const float*)d_in[13];
    float* out = (float*)d_out;

    float* ws = (float*)d_ws;
    float*          alpha_ws = ws;                               // RD f32
    float*          rgb_ws   = ws + (size_t)RD;                  // 3*RD f32
    unsigned short* k0b      = (unsigned short*)(ws + 4 * (size_t)RD);   // RD*16 u16
    float*          e_ws     = ws + 12 * (size_t)RD;             // RD f32
    unsigned short* w1f      = (unsigned short*)(ws + 13 * (size_t)RD);  // 16384 u16
    unsigned short* w0kf     = w1f + 16384;                      // 4096 u16
    unsigned short* w2f      = w0kf + 4096;                      // 2048 u16
    // vox at 64B-aligned offset after frags
    size_t frag_end = 13 * (size_t)RD * 4 + (16384 + 4096 + 2048) * 2;
    size_t vox_off  = (frag_end + 63) & ~(size_t)63;
    unsigned short* vox = (unsigned short*)((char*)d_ws + vox_off);
    size_t need = vox_off + (size_t)CSg * 64;
    bool use_aos = (ws_size >= need);

    k_prep_e<<<dim3(R_), dim3(WIDm), 0, stream>>>(rays_d, w0, b0, e_ws);
    k_prep_frags<<<dim3(88), dim3(256), 0, stream>>>(w0, w1, w2, w1f, w0kf, w2f);
    if (use_aos) {
        k_pack_vox<<<dim3((CSg + 255) / 256), dim3(256), 0, stream>>>(dg, pg, kg, vox);
        k_gather_aos<<<dim3(RD / 256), dim3(256), 0, stream>>>(
            rays_o, rays_d, vox, gfd, act_shift, alpha_ws, k0b);
    } else {
        k_gather_soa<<<dim3(RD / 256), dim3(256), 0, stream>>>(
            rays_o, rays_d, dg, pg, kg, gfd, act_shift, alpha_ws, k0b);
    }
    k_mlp<<<dim3(RD / 64), dim3(256), 0, stream>>>(
        k0b, e_ws, w0kf, w1f, w2f, b1, b2, gfr, rgb_ws);
    k_scan_reduce<<<dim3(R_ / 4), dim3(256), 0, stream>>>(alpha_ws, rgb_ws, out);
}

// Round 4
// 318.607 us; speedup vs baseline: 10.1740x; 1.0980x over previous
//
#include <hip/hip_runtime.h>
#include <math.h>

#define R_    8192
#define D_    128
#define RD    (R_ * D_)
#define NXg   160
#define NYg   160
#define NZg   128
#define CSg   (NXg * NYg * NZg)
#define WIDm  128
#define K0C   12
#define LAMc  0.01f
#define VSRc  2.0f

typedef __attribute__((ext_vector_type(8))) short   short8v;
typedef __attribute__((ext_vector_type(4))) float   f32x4;
typedef __attribute__((ext_vector_type(4))) unsigned short ushort4v;
typedef __attribute__((ext_vector_type(8))) unsigned short ushort8v;

static __device__ __forceinline__ unsigned short f2b(float f) {
    union { float f; unsigned int u; } v; v.f = f;
    unsigned int r = v.u + 0x7fffu + ((v.u >> 16) & 1u);   // RNE
    return (unsigned short)(r >> 16);
}
static __device__ __forceinline__ float b2f(unsigned short u) {
    union { unsigned int u; float f; } v; v.u = ((unsigned int)u) << 16;
    return v.f;
}

// ---------------- pack: 29 channel planes -> voxel-major AoS bf16, 4 voxels/thread --
__global__ __launch_bounds__(256) void k_pack_vox4(
    const float* __restrict__ dg, const float* __restrict__ pg,
    const float* __restrict__ kg, unsigned short* __restrict__ vox) {
    int v0 = (blockIdx.x * 256 + threadIdx.x) * 4;
    if (v0 >= CSg) return;                      // CSg % 4 == 0
    unsigned short rec[4][32];
    {
        f32x4 f = __builtin_nontemporal_load((const f32x4*)(dg + v0));
#pragma unroll
        for (int i = 0; i < 4; ++i) rec[i][0] = f2b(f[i]);
    }
#pragma unroll
    for (int c = 0; c < 16; ++c) {
        f32x4 f = __builtin_nontemporal_load((const f32x4*)(pg + (size_t)c * CSg + v0));
#pragma unroll
        for (int i = 0; i < 4; ++i) rec[i][1 + c] = f2b(f[i]);
    }
#pragma unroll
    for (int c = 0; c < K0C; ++c) {
        f32x4 f = __builtin_nontemporal_load((const f32x4*)(kg + (size_t)c * CSg + v0));
#pragma unroll
        for (int i = 0; i < 4; ++i) rec[i][17 + c] = f2b(f[i]);
    }
#pragma unroll
    for (int i = 0; i < 4; ++i) { rec[i][29] = 0; rec[i][30] = 0; rec[i][31] = 0; }
    unsigned short* dst = vox + (size_t)v0 * 32;
#pragma unroll
    for (int i = 0; i < 16; ++i)
        *(ushort8v*)(dst + i * 8) = *(ushort8v*)(&rec[i >> 2][(i & 3) * 8]);
}

// ---------------- prep A: per-ray embedding partial e[r][128] = emb@w0[0:27] + b0 ----
__global__ void k_prep_e(const float* __restrict__ rays_d,
                         const float* __restrict__ w0, const float* __restrict__ b0,
                         float* __restrict__ e) {
    int r = blockIdx.x;
    int j = threadIdx.x;
    float d0 = rays_d[r * 3 + 0], d1 = rays_d[r * 3 + 1], d2 = rays_d[r * 3 + 2];
    float nrm = sqrtf(d0 * d0 + d1 * d1 + d2 * d2) + 1e-8f;
    float v[3] = { d0 / nrm, d1 / nrm, d2 / nrm };
    float x[27];
    x[0] = v[0]; x[1] = v[1]; x[2] = v[2];
#pragma unroll
    for (int c = 0; c < 3; ++c)
#pragma unroll
        for (int f = 0; f < 4; ++f) {
            float ang = v[c] * (float)(1 << f);
            x[3 + c * 4 + f]  = sinf(ang);
            x[15 + c * 4 + f] = cosf(ang);
        }
    float acc = b0[j];
#pragma unroll
    for (int m = 0; m < 27; ++m) acc = fmaf(x[m], w0[m * WIDm + j], acc);
    e[r * WIDm + j] = acc;
}

// ---------------- prep B: pre-fragment weights into MFMA A-fragment order (bf16) ----
__global__ void k_prep_frags(const float* __restrict__ w0, const float* __restrict__ w1,
                             const float* __restrict__ w2,
                             unsigned short* __restrict__ w1f,
                             unsigned short* __restrict__ w0kf,
                             unsigned short* __restrict__ w2f) {
    int t = blockIdx.x * 256 + threadIdx.x;
    if (t < 16384) {                       // w1^T frags: 8 mt x 4 kc tiles
        int tile = t >> 9, lane = (t >> 3) & 63, j = t & 7;
        int mt = tile >> 2, kc = tile & 3;
        int k = kc * 32 + 8 * (lane >> 4) + j;
        int m = mt * 16 + (lane & 15);
        w1f[t] = f2b(w1[k * WIDm + m]);
    } else if (t < 16384 + 4096) {         // w0[27:39]^T frags
        int u = t - 16384;
        int mt = u >> 9, lane = (u >> 3) & 63, j = u & 7;
        int k = 8 * (lane >> 4) + j;
        int m = mt * 16 + (lane & 15);
        w0kf[u] = f2b(k < K0C ? w0[(27 + k) * WIDm + m] : 0.0f);
    } else if (t < 16384 + 4096 + 2048) {  // w2[:, 0:3]^T frags
        int u = t - 16384 - 4096;
        int kc = u >> 9, lane = (u >> 3) & 63, j = u & 7;
        int k = kc * 32 + 8 * (lane >> 4) + j;
        int m = lane & 15;
        w2f[u] = f2b(m < 3 ? w2[k * 78 + m] : 0.0f);
    }
}

// =============== shared per-sample math (density chain + alpha + k0 out) ===========
static __device__ __forceinline__ void finish_sample(
    int sid, int s, const float* acc /*29*/, const float* __restrict__ gfd,
    const float* __restrict__ act_shift,
    float* __restrict__ alpha_ws, unsigned short* __restrict__ k0b)
{
    float z = acc[0] + gfd[0] * LAMc;
#pragma unroll
    for (int i = 0; i < 4; ++i) {
        float pa = acc[1 + 4 * i + 0], pb = acc[1 + 4 * i + 1];
        float pc = acc[1 + 4 * i + 2], pd = acc[1 + 4 * i + 3];
        float sg = 1.0f / (1.0f + expf(-pd));
        z += pa * tanhf(pb * z + pc) * sg;
    }
    float den = z + act_shift[s];
    float sp = fmaxf(den, 0.0f) + log1pf(expf(-fabsf(den)));
    alpha_ws[sid] = 1.0f - expf(-sp * VSRc);

    ushort8v lo, hi;
#pragma unroll
    for (int c = 0; c < 8; ++c) lo[c] = f2b(acc[17 + c]);
#pragma unroll
    for (int c = 0; c < 8; ++c) hi[c] = (c < 4) ? f2b(acc[17 + 8 + c]) : (unsigned short)0;
    *(ushort8v*)(k0b + (size_t)sid * 16)     = lo;
    *(ushort8v*)(k0b + (size_t)sid * 16 + 8) = hi;
}

static __device__ __forceinline__ void sample_coords(
    int sid, const float* __restrict__ rays_o, const float* __restrict__ rays_d,
    int& ix, int& iy, int& iz, float& fx, float& fy, float& fz)
{
    int r = sid >> 7;
    int s = sid & 127;
    float t = s * (1.0f / 127.0f);
    float px = fminf(fmaxf(rays_o[r * 3 + 0] + rays_d[r * 3 + 0] * t, 0.0f), 1.0f);
    float py = fminf(fmaxf(rays_o[r * 3 + 1] + rays_d[r * 3 + 1] * t, 0.0f), 1.0f);
    float pz = fminf(fmaxf(rays_o[r * 3 + 2] + rays_d[r * 3 + 2] * t, 0.0f), 1.0f);
    float gx = px * (float)(NXg - 1);
    float gy = py * (float)(NYg - 1);
    float gz = pz * (float)(NZg - 1);
    ix = min((int)gx, NXg - 2);
    iy = min((int)gy, NYg - 2);
    iz = min((int)gz, NZg - 2);
    fx = gx - (float)ix;
    fy = gy - (float)iy;
    fz = gz - (float)iz;
}

// ---------------- K1a: AoS gather (preferred) --------------------------------------
__global__ __launch_bounds__(256) void k_gather_aos(
    const float* __restrict__ rays_o, const float* __restrict__ rays_d,
    const unsigned short* __restrict__ vox,
    const float* __restrict__ gfd, const float* __restrict__ act_shift,
    float* __restrict__ alpha_ws, unsigned short* __restrict__ k0b)
{
    int sid = blockIdx.x * 256 + threadIdx.x;
    if (sid >= RD) return;
    int ix, iy, iz; float fx, fy, fz;
    sample_coords(sid, rays_o, rays_d, ix, iy, iz, fx, fy, fz);

    const unsigned short* base = vox + ((size_t)(ix * NYg + iy) * NZg + iz) * 32;
    const size_t qoff[4] = { 0, (size_t)NZg * 32, (size_t)NYg * NZg * 32,
                             (size_t)(NYg + 1) * NZg * 32 };
    float wxy[4];
    wxy[0] = (1.0f - fx) * (1.0f - fy);
    wxy[1] = (1.0f - fx) * fy;
    wxy[2] = fx * (1.0f - fy);
    wxy[3] = fx * fy;
    float wz0 = 1.0f - fz, wz1 = fz;

    float acc[29];
#pragma unroll
    for (int c = 0; c < 29; ++c) acc[c] = 0.0f;

#pragma unroll
    for (int q = 0; q < 4; ++q) {
        const unsigned short* p = base + qoff[q];
#pragma unroll
        for (int dz = 0; dz < 2; ++dz) {
            float w = wxy[q] * (dz ? wz1 : wz0);
            const ushort8v* pv = (const ushort8v*)(p + dz * 32);
            ushort8v v0 = pv[0], v1 = pv[1], v2 = pv[2], v3 = pv[3];
#pragma unroll
            for (int i = 0; i < 8; ++i) acc[i]      = fmaf(w, b2f(v0[i]), acc[i]);
#pragma unroll
            for (int i = 0; i < 8; ++i) acc[8 + i]  = fmaf(w, b2f(v1[i]), acc[8 + i]);
#pragma unroll
            for (int i = 0; i < 8; ++i) acc[16 + i] = fmaf(w, b2f(v2[i]), acc[16 + i]);
#pragma unroll
            for (int i = 0; i < 5; ++i) acc[24 + i] = fmaf(w, b2f(v3[i]), acc[24 + i]);
        }
    }
    finish_sample(sid, sid & 127, acc, gfd, act_shift, alpha_ws, k0b);
}

// ---------------- K1b: SoA f32 gather (fallback when ws too small) -----------------
__global__ void k_gather_soa(
    const float* __restrict__ rays_o, const float* __restrict__ rays_d,
    const float* __restrict__ dg,  const float* __restrict__ pg,
    const float* __restrict__ kg,  const float* __restrict__ gfd,
    const float* __restrict__ act_shift,
    float* __restrict__ alpha_ws, unsigned short* __restrict__ k0b)
{
    int sid = blockIdx.x * 256 + threadIdx.x;
    if (sid >= RD) return;
    int ix, iy, iz; float fx, fy, fz;
    sample_coords(sid, rays_o, rays_d, ix, iy, iz, fx, fy, fz);

    int base = (ix * NYg + iy) * NZg + iz;
    int off[4] = { base, base + NZg, base + NYg * NZg, base + NYg * NZg + NZg };
    float wxy[4];
    wxy[0] = (1.0f - fx) * (1.0f - fy);
    wxy[1] = (1.0f - fx) * fy;
    wxy[2] = fx * (1.0f - fy);
    wxy[3] = fx * fy;
    float wz0 = 1.0f - fz, wz1 = fz;

    auto tri = [&](const float* __restrict__ g, int c) -> float {
        float a = 0.0f;
        const float* gc = g + (size_t)c * CSg;
#pragma unroll
        for (int q = 0; q < 4; ++q) {
            const float* p = gc + off[q];
            a += (p[0] * wz0 + p[1] * wz1) * wxy[q];
        }
        return a;
    };
    float acc[29];
    acc[0] = tri(dg, 0);
#pragma unroll
    for (int c = 0; c < 16; ++c) acc[1 + c] = tri(pg, c);
#pragma unroll
    for (int c = 0; c < K0C; ++c) acc[17 + c] = tri(kg, c);
    finish_sample(sid, sid & 127, acc, gfd, act_shift, alpha_ws, k0b);
}

// ---------------- K2: MFMA MLP -----------------------------------------------------
__global__ __launch_bounds__(256) void k_mlp(
    const unsigned short* __restrict__ k0b, const float* __restrict__ e,
    const unsigned short* __restrict__ w0kf, const unsigned short* __restrict__ w1f,
    const unsigned short* __restrict__ w2f,
    const float* __restrict__ b1, const float* __restrict__ b2,
    const float* __restrict__ gfr,
    float* __restrict__ rgb_ws)
{
    __shared__ unsigned short h0_lds[4][16][136];
    __shared__ unsigned short h1_lds[4][16][136];
    const int wid  = threadIdx.x >> 6;
    const int lane = threadIdx.x & 63;
    const int g    = lane >> 4;
    const int scol = lane & 15;
    const int sbase = blockIdx.x * 64 + wid * 16;
    const int ray   = sbase >> 7;

    const f32x4 zero4 = { 0.0f, 0.0f, 0.0f, 0.0f };

    short8v bf0 = { 0,0,0,0,0,0,0,0 };
    if (g < 2)
        bf0 = *(const short8v*)(k0b + ((size_t)(sbase + scol)) * 16 + g * 8);

    f32x4 acc0[8];
#pragma unroll
    for (int mt = 0; mt < 8; ++mt) {
        short8v af = *(const short8v*)(w0kf + (mt * 64 + lane) * 8);
        acc0[mt] = __builtin_amdgcn_mfma_f32_16x16x32_bf16(af, bf0, zero4, 0, 0, 0);
    }
#pragma unroll
    for (int mt = 0; mt < 8; ++mt) {
        f32x4 ev = *(const f32x4*)(e + ray * WIDm + mt * 16 + 4 * g);
        ushort4v pk;
#pragma unroll
        for (int i = 0; i < 4; ++i) {
            float v = acc0[mt][i] + ev[i];
            pk[i] = f2b(fmaxf(v, 0.0f));
        }
        *(ushort4v*)&h0_lds[wid][scol][mt * 16 + 4 * g] = pk;
    }
    __syncthreads();

    short8v bfr[4];
#pragma unroll
    for (int kc = 0; kc < 4; ++kc)
        bfr[kc] = *(const short8v*)&h0_lds[wid][scol][kc * 32 + 8 * g];

    f32x4 acc1[8];
#pragma unroll
    for (int mt = 0; mt < 8; ++mt) acc1[mt] = zero4;
#pragma unroll
    for (int mt = 0; mt < 8; ++mt)
#pragma unroll
        for (int kc = 0; kc < 4; ++kc) {
            short8v af = *(const short8v*)(w1f + ((mt * 4 + kc) * 64 + lane) * 8);
            acc1[mt] = __builtin_amdgcn_mfma_f32_16x16x32_bf16(af, bfr[kc], acc1[mt], 0, 0, 0);
        }
#pragma unroll
    for (int mt = 0; mt < 8; ++mt) {
        f32x4 bv = *(const f32x4*)(b1 + mt * 16 + 4 * g);
        ushort4v pk;
#pragma unroll
        for (int i = 0; i < 4; ++i) {
            float v = acc1[mt][i] + bv[i];
            pk[i] = f2b(fmaxf(v, 0.0f));
        }
        *(ushort4v*)&h1_lds[wid][scol][mt * 16 + 4 * g] = pk;
    }
    __syncthreads();

    short8v cfr[4];
#pragma unroll
    for (int kc = 0; kc < 4; ++kc)
        cfr[kc] = *(const short8v*)&h1_lds[wid][scol][kc * 32 + 8 * g];

    f32x4 acc2 = zero4;
#pragma unroll
    for (int kc = 0; kc < 4; ++kc) {
        short8v af = *(const short8v*)(w2f + (kc * 64 + lane) * 8);
        acc2 = __builtin_amdgcn_mfma_f32_16x16x32_bf16(af, cfr[kc], acc2, 0, 0, 0);
    }
    if (lane < 16) {
        int sid = sbase + lane;
#pragma unroll
        for (int c = 0; c < 3; ++c) {
            float v = acc2[c] + b2[c] + gfr[c] * LAMc;
            rgb_ws[(size_t)c * RD + sid] = 1.0f / (1.0f + expf(-v));
        }
    }
}

// ---------------- K3: per-ray transmittance scan + weighted RGB reduce -------------
__global__ void k_scan_reduce(const float* __restrict__ alpha_ws,
                              const float* __restrict__ rgb_ws,
                              float* __restrict__ out)
{
    int gtid = blockIdx.x * 256 + threadIdx.x;
    int r = gtid >> 6;
    int lane = gtid & 63;
    if (r >= R_) return;

    int base = r * D_ + lane * 2;
    float a0 = alpha_ws[base];
    float a1 = alpha_ws[base + 1];
    float q0 = 1.0f - a0 + 1e-10f;
    float q1 = 1.0f - a1 + 1e-10f;
    float p = q0 * q1;

    float incl = p;
#pragma unroll
    for (int o = 1; o < 64; o <<= 1) {
        float v = __shfl_up(incl, o);
        if (lane >= o) incl *= v;
    }
    float excl = __shfl_up(incl, 1);
    if (lane == 0) excl = 1.0f;
    float Tlast = __shfl(incl, 63);

    float w0s = a0 * excl;
    float w1s = a1 * excl * q0;

    float sums[3];
#pragma unroll
    for (int c = 0; c < 3; ++c) {
        float rg0 = rgb_ws[(size_t)c * RD + base];
        float rg1 = rgb_ws[(size_t)c * RD + base + 1];
        float sc = w0s * rg0 + w1s * rg1;
#pragma unroll
        for (int o = 32; o >= 1; o >>= 1) sc += __shfl_xor(sc, o);
        sums[c] = sc;
    }
    if (lane == 0) {
#pragma unroll
        for (int c = 0; c < 3; ++c) out[r * 3 + c] = sums[c] + Tlast;
    }
}

extern "C" void kernel_launch(void* const* d_in, const int* in_sizes, int n_in,
                              void* d_out, int out_size, void* d_ws, size_t ws_size,
                              hipStream_t stream) {
    const float* rays_o    = (const float*)d_in[0];
    const float* rays_d    = (const float*)d_in[1];
    const float* dg        = (const float*)d_in[2];
    const float* pg        = (const float*)d_in[3];
    const float* kg        = (const float*)d_in[4];
    const float* gfd       = (const float*)d_in[5];
    const float* gfr       = (const float*)d_in[6];
    const float* w0        = (const float*)d_in[7];
    const float* b0        = (const float*)d_in[8];
    const float* w1        = (const float*)d_in[9];
    const float* b1        = (const float*)d_in[10];
    const float* w2        = (const float*)d_in[11];
    const float* b2        = (const float*)d_in[12];
    const float* act_shift = (const float*)d_in[13];
    float* out = (float*)d_out;

    float* ws = (float*)d_ws;
    float*          alpha_ws = ws;                               // RD f32
    float*          rgb_ws   = ws + (size_t)RD;                  // 3*RD f32
    unsigned short* k0b      = (unsigned short*)(ws + 4 * (size_t)RD);   // RD*16 u16
    float*          e_ws     = ws + 12 * (size_t)RD;             // RD f32
    unsigned short* w1f      = (unsigned short*)(ws + 13 * (size_t)RD);  // 16384 u16
    unsigned short* w0kf     = w1f + 16384;                      // 4096 u16
    unsigned short* w2f      = w0kf + 4096;                      // 2048 u16
    size_t frag_end = 13 * (size_t)RD * 4 + (16384 + 4096 + 2048) * 2;
    size_t vox_off  = (frag_end + 63) & ~(size_t)63;
    unsigned short* vox = (unsigned short*)((char*)d_ws + vox_off);
    size_t need = vox_off + (size_t)CSg * 64;
    bool use_aos = (ws_size >= need);

    k_prep_e<<<dim3(R_), dim3(WIDm), 0, stream>>>(rays_d, w0, b0, e_ws);
    k_prep_frags<<<dim3(88), dim3(256), 0, stream>>>(w0, w1, w2, w1f, w0kf, w2f);
    if (use_aos) {
        k_pack_vox4<<<dim3(CSg / 1024), dim3(256), 0, stream>>>(dg, pg, kg, vox);
        k_gather_aos<<<dim3(RD / 256), dim3(256), 0, stream>>>(
            rays_o, rays_d, vox, gfd, act_shift, alpha_ws, k0b);
    } else {
        k_gather_soa<<<dim3(RD / 256), dim3(256), 0, stream>>>(
            rays_o, rays_d, dg, pg, kg, gfd, act_shift, alpha_ws, k0b);
    }
    k_mlp<<<dim3(RD / 64), dim3(256), 0, stream>>>(
        k0b, e_ws, w0kf, w1f, w2f, b1, b2, gfr, rgb_ws);
    k_scan_reduce<<<dim3(R_ / 4), dim3(256), 0, stream>>>(alpha_ws, rgb_ws, out);
}

// Round 5
// 262.566 us; speedup vs baseline: 12.3456x; 1.2134x over previous
//
#include <hip/hip_runtime.h>
#include <math.h>

#define R_    8192
#define D_    128
#define RD    (R_ * D_)
#define NXg   160
#define NYg   160
#define NZg   128
#define CSg   (NXg * NYg * NZg)
#define WIDm  128
#define K0C   12
#define LAMc  0.01f
#define VSRc  2.0f

// frag table sizes (shorts): w1f | w0kf | w2f contiguous
#define W1F_N   16384
#define W0KF_N  2048
#define W2F_N   4096
#define WTAB_N  (W1F_N + W0KF_N + W2F_N)   // 22528 shorts = 45056 B
#define LW1     0
#define LW0K    W1F_N
#define LW2     (W1F_N + W0KF_N)

typedef __attribute__((ext_vector_type(8)))  short   short8v;
typedef __attribute__((ext_vector_type(4)))  float   f32x4;
typedef __attribute__((ext_vector_type(16))) float   f32x16;
typedef __attribute__((ext_vector_type(2)))  int     int2v;
typedef __attribute__((ext_vector_type(4)))  int     int4v;
typedef __attribute__((ext_vector_type(4)))  unsigned short ushort4v;
typedef __attribute__((ext_vector_type(8)))  unsigned short ushort8v;

static __device__ __forceinline__ unsigned short f2b(float f) {
    union { float f; unsigned int u; } v; v.f = f;
    unsigned int r = v.u + 0x7fffu + ((v.u >> 16) & 1u);   // RNE
    return (unsigned short)(r >> 16);
}
static __device__ __forceinline__ float b2f(unsigned short u) {
    union { unsigned int u; float f; } v; v.u = ((unsigned int)u) << 16;
    return v.f;
}
static __device__ __forceinline__ unsigned int pk2(float lo, float hi) {
    unsigned int r;
    asm("v_cvt_pk_bf16_f32 %0, %1, %2" : "=v"(r) : "v"(lo), "v"(hi));
    return r;
}
static __device__ __forceinline__ short8v as_s8(int4v v) {
    union { int4v i; short8v s; } u; u.i = v; return u.s;
}

// ---------------- pack: 29 channel planes -> voxel-major AoS bf16, 4 voxels/thread --
__global__ __launch_bounds__(256) void k_pack_vox4(
    const float* __restrict__ dg, const float* __restrict__ pg,
    const float* __restrict__ kg, unsigned short* __restrict__ vox) {
    int v0 = (blockIdx.x * 256 + threadIdx.x) * 4;
    if (v0 >= CSg) return;
    unsigned short rec[4][32];
    {
        f32x4 f = __builtin_nontemporal_load((const f32x4*)(dg + v0));
#pragma unroll
        for (int i = 0; i < 4; ++i) rec[i][0] = f2b(f[i]);
    }
#pragma unroll
    for (int c = 0; c < 16; ++c) {
        f32x4 f = __builtin_nontemporal_load((const f32x4*)(pg + (size_t)c * CSg + v0));
#pragma unroll
        for (int i = 0; i < 4; ++i) rec[i][1 + c] = f2b(f[i]);
    }
#pragma unroll
    for (int c = 0; c < K0C; ++c) {
        f32x4 f = __builtin_nontemporal_load((const f32x4*)(kg + (size_t)c * CSg + v0));
#pragma unroll
        for (int i = 0; i < 4; ++i) rec[i][17 + c] = f2b(f[i]);
    }
#pragma unroll
    for (int i = 0; i < 4; ++i) { rec[i][29] = 0; rec[i][30] = 0; rec[i][31] = 0; }
    unsigned short* dst = vox + (size_t)v0 * 32;
#pragma unroll
    for (int i = 0; i < 16; ++i)
        *(ushort8v*)(dst + i * 8) = *(ushort8v*)(&rec[i >> 2][(i & 3) * 8]);
}

// ---------------- prep A: per-ray embedding partial e[r][128] = emb@w0[0:27] + b0 ----
__global__ void k_prep_e(const float* __restrict__ rays_d,
                         const float* __restrict__ w0, const float* __restrict__ b0,
                         float* __restrict__ e) {
    int r = blockIdx.x;
    int j = threadIdx.x;
    float d0 = rays_d[r * 3 + 0], d1 = rays_d[r * 3 + 1], d2 = rays_d[r * 3 + 2];
    float nrm = sqrtf(d0 * d0 + d1 * d1 + d2 * d2) + 1e-8f;
    float v[3] = { d0 / nrm, d1 / nrm, d2 / nrm };
    float x[27];
    x[0] = v[0]; x[1] = v[1]; x[2] = v[2];
#pragma unroll
    for (int c = 0; c < 3; ++c)
#pragma unroll
        for (int f = 0; f < 4; ++f) {
            float ang = v[c] * (float)(1 << f);
            x[3 + c * 4 + f]  = sinf(ang);
            x[15 + c * 4 + f] = cosf(ang);
        }
    float acc = b0[j];
#pragma unroll
    for (int m = 0; m < 27; ++m) acc = fmaf(x[m], w0[m * WIDm + j], acc);
    e[r * WIDm + j] = acc;
}

// ------- prep B: pre-fragment weights into 32x32x16 MFMA A-fragment order (bf16) ----
// A-frag mapping (32x32x16): lane l holds row m=(l&31), k = 8*(l>>5)+j, j=0..7
__global__ void k_prep_frags32(const float* __restrict__ w0, const float* __restrict__ w1,
                               const float* __restrict__ w2,
                               unsigned short* __restrict__ wtab) {
    int t = blockIdx.x * 256 + threadIdx.x;
    if (t < W1F_N) {                       // w1 A-frags: tiles (mt,ks), 4x8
        int tile = t >> 9, l = (t >> 3) & 63, j = t & 7;
        int mt = tile >> 3, ks = tile & 7;
        int m = mt * 32 + (l & 31);
        int k = ks * 16 + 8 * (l >> 5) + j;
        wtab[LW1 + t] = f2b(w1[k * WIDm + m]);
    } else if (t < W1F_N + W0KF_N) {       // w0[27:39] A-frags: 4 mt tiles, K=16 (pad)
        int u = t - W1F_N;
        int mt = u >> 9, l = (u >> 3) & 63, j = u & 7;
        int m = mt * 32 + (l & 31);
        int k = 8 * (l >> 5) + j;
        wtab[LW0K + u] = f2b(k < K0C ? w0[(27 + k) * WIDm + m] : 0.0f);
    } else {                               // w2[:,0:3] A-frags: 8 ks tiles, M=32 (pad)
        int u = t - W1F_N - W0KF_N;
        int ks = u >> 9, l = (u >> 3) & 63, j = u & 7;
        int m = l & 31;
        int k = ks * 16 + 8 * (l >> 5) + j;
        wtab[LW2 + u] = f2b(m < 3 ? w2[k * 78 + m] : 0.0f);
    }
}

// =============== shared per-sample math (density chain + alpha + k0 out) ===========
static __device__ __forceinline__ void finish_sample(
    int sid, int s, const float* acc /*29*/, const float* __restrict__ gfd,
    const float* __restrict__ act_shift,
    float* __restrict__ alpha_ws, unsigned short* __restrict__ k0b)
{
    float z = acc[0] + gfd[0] * LAMc;
#pragma unroll
    for (int i = 0; i < 4; ++i) {
        float pa = acc[1 + 4 * i + 0], pb = acc[1 + 4 * i + 1];
        float pc = acc[1 + 4 * i + 2], pd = acc[1 + 4 * i + 3];
        float sg = 1.0f / (1.0f + expf(-pd));
        z += pa * tanhf(pb * z + pc) * sg;
    }
    float den = z + act_shift[s];
    float sp = fmaxf(den, 0.0f) + log1pf(expf(-fabsf(den)));
    alpha_ws[sid] = 1.0f - expf(-sp * VSRc);

    ushort8v lo, hi;
#pragma unroll
    for (int c = 0; c < 8; ++c) lo[c] = f2b(acc[17 + c]);
#pragma unroll
    for (int c = 0; c < 8; ++c) hi[c] = (c < 4) ? f2b(acc[17 + 8 + c]) : (unsigned short)0;
    *(ushort8v*)(k0b + (size_t)sid * 16)     = lo;
    *(ushort8v*)(k0b + (size_t)sid * 16 + 8) = hi;
}

static __device__ __forceinline__ void sample_coords(
    int sid, const float* __restrict__ rays_o, const float* __restrict__ rays_d,
    int& ix, int& iy, int& iz, float& fx, float& fy, float& fz)
{
    int r = sid >> 7;
    int s = sid & 127;
    float t = s * (1.0f / 127.0f);
    float px = fminf(fmaxf(rays_o[r * 3 + 0] + rays_d[r * 3 + 0] * t, 0.0f), 1.0f);
    float py = fminf(fmaxf(rays_o[r * 3 + 1] + rays_d[r * 3 + 1] * t, 0.0f), 1.0f);
    float pz = fminf(fmaxf(rays_o[r * 3 + 2] + rays_d[r * 3 + 2] * t, 0.0f), 1.0f);
    float gx = px * (float)(NXg - 1);
    float gy = py * (float)(NYg - 1);
    float gz = pz * (float)(NZg - 1);
    ix = min((int)gx, NXg - 2);
    iy = min((int)gy, NYg - 2);
    iz = min((int)gz, NZg - 2);
    fx = gx - (float)ix;
    fy = gy - (float)iy;
    fz = gz - (float)iz;
}

// ---------------- K1a: AoS gather (preferred) --------------------------------------
__global__ __launch_bounds__(256) void k_gather_aos(
    const float* __restrict__ rays_o, const float* __restrict__ rays_d,
    const unsigned short* __restrict__ vox,
    const float* __restrict__ gfd, const float* __restrict__ act_shift,
    float* __restrict__ alpha_ws, unsigned short* __restrict__ k0b)
{
    int sid = blockIdx.x * 256 + threadIdx.x;
    if (sid >= RD) return;
    int ix, iy, iz; float fx, fy, fz;
    sample_coords(sid, rays_o, rays_d, ix, iy, iz, fx, fy, fz);

    const unsigned short* base = vox + ((size_t)(ix * NYg + iy) * NZg + iz) * 32;
    const size_t qoff[4] = { 0, (size_t)NZg * 32, (size_t)NYg * NZg * 32,
                             (size_t)(NYg + 1) * NZg * 32 };
    float wxy[4];
    wxy[0] = (1.0f - fx) * (1.0f - fy);
    wxy[1] = (1.0f - fx) * fy;
    wxy[2] = fx * (1.0f - fy);
    wxy[3] = fx * fy;
    float wz0 = 1.0f - fz, wz1 = fz;

    float acc[29];
#pragma unroll
    for (int c = 0; c < 29; ++c) acc[c] = 0.0f;

#pragma unroll
    for (int q = 0; q < 4; ++q) {
        const unsigned short* p = base + qoff[q];
#pragma unroll
        for (int dz = 0; dz < 2; ++dz) {
            float w = wxy[q] * (dz ? wz1 : wz0);
            const ushort8v* pv = (const ushort8v*)(p + dz * 32);
            ushort8v v0 = pv[0], v1 = pv[1], v2 = pv[2], v3 = pv[3];
#pragma unroll
            for (int i = 0; i < 8; ++i) acc[i]      = fmaf(w, b2f(v0[i]), acc[i]);
#pragma unroll
            for (int i = 0; i < 8; ++i) acc[8 + i]  = fmaf(w, b2f(v1[i]), acc[8 + i]);
#pragma unroll
            for (int i = 0; i < 8; ++i) acc[16 + i] = fmaf(w, b2f(v2[i]), acc[16 + i]);
#pragma unroll
            for (int i = 0; i < 5; ++i) acc[24 + i] = fmaf(w, b2f(v3[i]), acc[24 + i]);
        }
    }
    finish_sample(sid, sid & 127, acc, gfd, act_shift, alpha_ws, k0b);
}

// ---------------- K1b: SoA f32 gather (fallback when ws too small) -----------------
__global__ void k_gather_soa(
    const float* __restrict__ rays_o, const float* __restrict__ rays_d,
    const float* __restrict__ dg,  const float* __restrict__ pg,
    const float* __restrict__ kg,  const float* __restrict__ gfd,
    const float* __restrict__ act_shift,
    float* __restrict__ alpha_ws, unsigned short* __restrict__ k0b)
{
    int sid = blockIdx.x * 256 + threadIdx.x;
    if (sid >= RD) return;
    int ix, iy, iz; float fx, fy, fz;
    sample_coords(sid, rays_o, rays_d, ix, iy, iz, fx, fy, fz);

    int base = (ix * NYg + iy) * NZg + iz;
    int off[4] = { base, base + NZg, base + NYg * NZg, base + NYg * NZg + NZg };
    float wxy[4];
    wxy[0] = (1.0f - fx) * (1.0f - fy);
    wxy[1] = (1.0f - fx) * fy;
    wxy[2] = fx * (1.0f - fy);
    wxy[3] = fx * fy;
    float wz0 = 1.0f - fz, wz1 = fz;

    auto tri = [&](const float* __restrict__ g, int c) -> float {
        float a = 0.0f;
        const float* gc = g + (size_t)c * CSg;
#pragma unroll
        for (int q = 0; q < 4; ++q) {
            const float* p = gc + off[q];
            a += (p[0] * wz0 + p[1] * wz1) * wxy[q];
        }
        return a;
    };
    float acc[29];
    acc[0] = tri(dg, 0);
#pragma unroll
    for (int c = 0; c < 16; ++c) acc[1 + c] = tri(pg, c);
#pragma unroll
    for (int c = 0; c < K0C; ++c) acc[17 + c] = tri(kg, c);
    finish_sample(sid, sid & 127, acc, gfd, act_shift, alpha_ws, k0b);
}

// ---------------- K2: MFMA MLP, 32x32x16, in-register permlane transpose -----------
// C/D layout (32x32): col = lane&31, row = (r&3) + 8*(r>>2) + 4*(lane>>5)  [m74/m101]
// A/B layout: row/col = lane&31, k = 8*(lane>>5) + j
struct BPair { int4v lo, hi; };

static __device__ __forceinline__ BPair ttile(const f32x16 v) {
    unsigned p[8];
#pragma unroll
    for (int q = 0; q < 8; ++q) p[q] = pk2(v[2 * q], v[2 * q + 1]);
    int2v a = __builtin_amdgcn_permlane32_swap((int)p[0], (int)p[2], false, false);
    int2v b = __builtin_amdgcn_permlane32_swap((int)p[1], (int)p[3], false, false);
    int2v c = __builtin_amdgcn_permlane32_swap((int)p[4], (int)p[6], false, false);
    int2v d = __builtin_amdgcn_permlane32_swap((int)p[5], (int)p[7], false, false);
    BPair r;
    r.lo = int4v{ a.x, b.x, a.y, b.y };   // B-frag for k-step 2*mt
    r.hi = int4v{ c.x, d.x, c.y, d.y };   // B-frag for k-step 2*mt+1
    return r;
}

__global__ __launch_bounds__(256) void k_mlp32(
    const unsigned short* __restrict__ k0b, const float* __restrict__ e,
    const unsigned short* __restrict__ wtab,
    const float* __restrict__ b1, const float* __restrict__ b2,
    const float* __restrict__ gfr,
    float* __restrict__ rgb_ws)
{
    __shared__ unsigned short wlds[WTAB_N];      // 45056 B, staged once per block
#pragma unroll
    for (int it = 0; it < WTAB_N / (256 * 8); ++it) {
        int i = (it * 256 + threadIdx.x) * 8;
        *(ushort8v*)&wlds[i] = *(const ushort8v*)&wtab[i];
    }
    __syncthreads();

    const int lane = threadIdx.x & 63;
    const int wid  = threadIdx.x >> 6;
    const int n    = lane & 31;
    const int h    = lane >> 5;
    const int sbase = blockIdx.x * 128 + wid * 32;   // one ray per block
    const int sid   = sbase + n;
    const int ray   = blockIdx.x;

    // ---- layer 0: C-init = e[ray][.] (contains emb@w0[0:27]+b0), A = w0k, B = k0 --
    f32x16 acc0[4];
#pragma unroll
    for (int mt = 0; mt < 4; ++mt) {
        const f32x4* ep = (const f32x4*)(e + (size_t)ray * WIDm + mt * 32 + 4 * h);
#pragma unroll
        for (int rr = 0; rr < 4; ++rr) {
            f32x4 ev = ep[2 * rr];
#pragma unroll
            for (int q = 0; q < 4; ++q) acc0[mt][rr * 4 + q] = ev[q];
        }
    }
    short8v bk = *(const short8v*)(k0b + (size_t)sid * 16 + h * 8);
#pragma unroll
    for (int mt = 0; mt < 4; ++mt) {
        short8v af = *(const short8v*)&wlds[LW0K + (mt * 64 + lane) * 8];
        acc0[mt] = __builtin_amdgcn_mfma_f32_32x32x16_bf16(af, bk, acc0[mt], 0, 0, 0);
    }
    // relu + in-register transpose -> B-frags for layer 1
    int4v bw[8];
#pragma unroll
    for (int mt = 0; mt < 4; ++mt) {
        f32x16 hv;
#pragma unroll
        for (int r = 0; r < 16; ++r) hv[r] = fmaxf(acc0[mt][r], 0.0f);
        BPair t = ttile(hv);
        bw[2 * mt]     = t.lo;
        bw[2 * mt + 1] = t.hi;
    }

    // ---- layer 1: C-init = b1, A = w1 frags, B = bw ----
    f32x16 acc1[4];
#pragma unroll
    for (int mt = 0; mt < 4; ++mt) {
        const f32x4* bp = (const f32x4*)(b1 + mt * 32 + 4 * h);
#pragma unroll
        for (int rr = 0; rr < 4; ++rr) {
            f32x4 bv = bp[2 * rr];
#pragma unroll
            for (int q = 0; q < 4; ++q) acc1[mt][rr * 4 + q] = bv[q];
        }
    }
#pragma unroll
    for (int mt = 0; mt < 4; ++mt)
#pragma unroll
        for (int ks = 0; ks < 8; ++ks) {
            short8v af = *(const short8v*)&wlds[LW1 + ((mt * 8 + ks) * 64 + lane) * 8];
            acc1[mt] = __builtin_amdgcn_mfma_f32_32x32x16_bf16(af, as_s8(bw[ks]), acc1[mt], 0, 0, 0);
        }
    // relu + transpose -> B-frags for layer 2
    int4v cw[8];
#pragma unroll
    for (int mt = 0; mt < 4; ++mt) {
        f32x16 hv;
#pragma unroll
        for (int r = 0; r < 16; ++r) hv[r] = fmaxf(acc1[mt][r], 0.0f);
        BPair t = ttile(hv);
        cw[2 * mt]     = t.lo;
        cw[2 * mt + 1] = t.hi;
    }

    // ---- layer 2: rgb rows 0..2 ----
    f32x16 acc2;
#pragma unroll
    for (int r = 0; r < 16; ++r) acc2[r] = 0.0f;
#pragma unroll
    for (int ks = 0; ks < 8; ++ks) {
        short8v af = *(const short8v*)&wlds[LW2 + (ks * 64 + lane) * 8];
        acc2 = __builtin_amdgcn_mfma_f32_32x32x16_bf16(af, as_s8(cw[ks]), acc2, 0, 0, 0);
    }
    if (h == 0) {   // rows 0..2 live in regs 0..2 of lanes 0..31
#pragma unroll
        for (int c = 0; c < 3; ++c) {
            float v = acc2[c] + b2[c] + gfr[c] * LAMc;
            rgb_ws[(size_t)c * RD + sid] = 1.0f / (1.0f + expf(-v));
        }
    }
}

// ---------------- K3: per-ray transmittance scan + weighted RGB reduce -------------
__global__ void k_scan_reduce(const float* __restrict__ alpha_ws,
                              const float* __restrict__ rgb_ws,
                              float* __restrict__ out)
{
    int gtid = blockIdx.x * 256 + threadIdx.x;
    int r = gtid >> 6;
    int lane = gtid & 63;
    if (r >= R_) return;

    int base = r * D_ + lane * 2;
    float a0 = alpha_ws[base];
    float a1 = alpha_ws[base + 1];
    float q0 = 1.0f - a0 + 1e-10f;
    float q1 = 1.0f - a1 + 1e-10f;
    float p = q0 * q1;

    float incl = p;
#pragma unroll
    for (int o = 1; o < 64; o <<= 1) {
        float v = __shfl_up(incl, o);
        if (lane >= o) incl *= v;
    }
    float excl = __shfl_up(incl, 1);
    if (lane == 0) excl = 1.0f;
    float Tlast = __shfl(incl, 63);

    float w0s = a0 * excl;
    float w1s = a1 * excl * q0;

    float sums[3];
#pragma unroll
    for (int c = 0; c < 3; ++c) {
        float rg0 = rgb_ws[(size_t)c * RD + base];
        float rg1 = rgb_ws[(size_t)c * RD + base + 1];
        float sc = w0s * rg0 + w1s * rg1;
#pragma unroll
        for (int o = 32; o >= 1; o >>= 1) sc += __shfl_xor(sc, o);
        sums[c] = sc;
    }
    if (lane == 0) {
#pragma unroll
        for (int c = 0; c < 3; ++c) out[r * 3 + c] = sums[c] + Tlast;
    }
}

extern "C" void kernel_launch(void* const* d_in, const int* in_sizes, int n_in,
                              void* d_out, int out_size, void* d_ws, size_t ws_size,
                              hipStream_t stream) {
    const float* rays_o    = (const float*)d_in[0];
    const float* rays_d    = (const float*)d_in[1];
    const float* dg        = (const float*)d_in[2];
    const float* pg        = (const float*)d_in[3];
    const float* kg        = (const float*)d_in[4];
    const float* gfd       = (const float*)d_in[5];
    const float* gfr       = (const float*)d_in[6];
    const float* w0        = (const float*)d_in[7];
    const float* b0        = (const float*)d_in[8];
    const float* w1        = (const float*)d_in[9];
    const float* b1        = (const float*)d_in[10];
    const float* w2        = (const float*)d_in[11];
    const float* b2        = (const float*)d_in[12];
    const float* act_shift = (const float*)d_in[13];
    float* out = (float*)d_out;

    float* ws = (float*)d_ws;
    float*          alpha_ws = ws;                               // RD f32
    float*          rgb_ws   = ws + (size_t)RD;                  // 3*RD f32
    unsigned short* k0b      = (unsigned short*)(ws + 4 * (size_t)RD);   // RD*16 u16
    float*          e_ws     = ws + 12 * (size_t)RD;             // RD f32
    unsigned short* wtab     = (unsigned short*)(ws + 13 * (size_t)RD);  // 22528 u16
    size_t frag_end = 13 * (size_t)RD * 4 + (size_t)WTAB_N * 2;
    size_t vox_off  = (frag_end + 63) & ~(size_t)63;
    unsigned short* vox = (unsigned short*)((char*)d_ws + vox_off);
    size_t need = vox_off + (size_t)CSg * 64;
    bool use_aos = (ws_size >= need);

    k_prep_e<<<dim3(R_), dim3(WIDm), 0, stream>>>(rays_d, w0, b0, e_ws);
    k_prep_frags32<<<dim3(WTAB_N / 256), dim3(256), 0, stream>>>(w0, w1, w2, wtab);
    if (use_aos) {
        k_pack_vox4<<<dim3(CSg / 1024), dim3(256), 0, stream>>>(dg, pg, kg, vox);
        k_gather_aos<<<dim3(RD / 256), dim3(256), 0, stream>>>(
            rays_o, rays_d, vox, gfd, act_shift, alpha_ws, k0b);
    } else {
        k_gather_soa<<<dim3(RD / 256), dim3(256), 0, stream>>>(
            rays_o, rays_d, dg, pg, kg, gfd, act_shift, alpha_ws, k0b);
    }
    k_mlp32<<<dim3(R_), dim3(256), 0, stream>>>(
        k0b, e_ws, wtab, b1, b2, gfr, rgb_ws);
    k_scan_reduce<<<dim3(R_ / 4), dim3(256), 0, stream>>>(alpha_ws, rgb_ws, out);
}

// Round 6
// 258.703 us; speedup vs baseline: 12.5299x; 1.0149x over previous
//
#include <hip/hip_runtime.h>
#include <math.h>

#define R_    8192
#define D_    128
#define RD    (R_ * D_)
#define NXg   160
#define NYg   160
#define NZg   128
#define CSg   (NXg * NYg * NZg)
#define WIDm  128
#define K0C   12
#define LAMc  0.01f
#define VSRc  2.0f

// frag table sizes (shorts): w1f | w0kf | w2f contiguous
#define W1F_N   16384
#define W0KF_N  2048
#define W2F_N   4096
#define WTAB_N  (W1F_N + W0KF_N + W2F_N)   // 22528 shorts = 45056 B
#define LW1     0
#define LW0K    W1F_N
#define LW2     (W1F_N + W0KF_N)

typedef __attribute__((ext_vector_type(8)))  short   short8v;
typedef __attribute__((ext_vector_type(4)))  float   f32x4;
typedef __attribute__((ext_vector_type(16))) float   f32x16;
typedef __attribute__((ext_vector_type(2)))  int     int2v;
typedef __attribute__((ext_vector_type(4)))  int     int4v;
typedef __attribute__((ext_vector_type(4)))  unsigned short ushort4v;
typedef __attribute__((ext_vector_type(8)))  unsigned short ushort8v;

static __device__ __forceinline__ unsigned short f2b(float f) {
    union { float f; unsigned int u; } v; v.f = f;
    unsigned int r = v.u + 0x7fffu + ((v.u >> 16) & 1u);   // RNE
    return (unsigned short)(r >> 16);
}
static __device__ __forceinline__ float b2f(unsigned short u) {
    union { unsigned int u; float f; } v; v.u = ((unsigned int)u) << 16;
    return v.f;
}
static __device__ __forceinline__ unsigned int pk2(float lo, float hi) {
    unsigned int r;
    asm("v_cvt_pk_bf16_f32 %0, %1, %2" : "=v"(r) : "v"(lo), "v"(hi));
    return r;
}
static __device__ __forceinline__ short8v as_s8(int4v v) {
    union { int4v i; short8v s; } u; u.i = v; return u.s;
}

// ---------------- pack: chunk-transposed, line-perfect loads AND stores ------------
// lane: g = tid&3 owns channel-chunk g (8 channels = 16 B of the 64 B record)
//       for voxels vb + 4*(tid>>2) + {0..3}.
// store instr k: lanes 0..3 cover one full 64 B line -> 16 full lines/instr.
// load  instr q: 4 planes x 16 lanes x 16 B contiguous -> fully coalesced.
__global__ __launch_bounds__(256) void k_pack_t(
    const float* __restrict__ dg, const float* __restrict__ pg,
    const float* __restrict__ kg, unsigned short* __restrict__ vox)
{
    const int tid = threadIdx.x;
    const int g   = tid & 3;
    const int s2  = tid >> 2;          // 0..63
    const float* pl[8];
    bool padq[8];
#pragma unroll
    for (int q = 0; q < 8; ++q) {
        int ch = 8 * g + q;
        padq[q] = (ch >= 29);
        pl[q] = (ch == 0) ? dg
              : (ch < 17) ? pg + (size_t)(ch - 1) * CSg
              : (ch < 29) ? kg + (size_t)(ch - 17) * CSg
              : dg;
    }
#pragma unroll
    for (int it = 0; it < 4; ++it) {
        int vofs = (blockIdx.x * 4 + it) * 256 + 4 * s2;
        f32x4 L[8];
#pragma unroll
        for (int q = 0; q < 8; ++q) {
            f32x4 v = __builtin_nontemporal_load((const f32x4*)(pl[q] + vofs));
            if (padq[q]) v = f32x4{0.0f, 0.0f, 0.0f, 0.0f};
            L[q] = v;
        }
#pragma unroll
        for (int k = 0; k < 4; ++k) {
            int4v chunk;
#pragma unroll
            for (int h2 = 0; h2 < 4; ++h2)
                chunk[h2] = (int)pk2(L[2 * h2][k], L[2 * h2 + 1][k]);
            *(int4v*)((char*)vox + (size_t)(vofs + k) * 64 + g * 16) = chunk;
        }
    }
}

// ---------------- prep A: per-ray embedding partial e[r][128] = emb@w0[0:27] + b0 ----
__global__ void k_prep_e(const float* __restrict__ rays_d,
                         const float* __restrict__ w0, const float* __restrict__ b0,
                         float* __restrict__ e) {
    int r = blockIdx.x;
    int j = threadIdx.x;
    float d0 = rays_d[r * 3 + 0], d1 = rays_d[r * 3 + 1], d2 = rays_d[r * 3 + 2];
    float nrm = sqrtf(d0 * d0 + d1 * d1 + d2 * d2) + 1e-8f;
    float v[3] = { d0 / nrm, d1 / nrm, d2 / nrm };
    float x[27];
    x[0] = v[0]; x[1] = v[1]; x[2] = v[2];
#pragma unroll
    for (int c = 0; c < 3; ++c)
#pragma unroll
        for (int f = 0; f < 4; ++f) {
            float ang = v[c] * (float)(1 << f);
            x[3 + c * 4 + f]  = sinf(ang);
            x[15 + c * 4 + f] = cosf(ang);
        }
    float acc = b0[j];
#pragma unroll
    for (int m = 0; m < 27; ++m) acc = fmaf(x[m], w0[m * WIDm + j], acc);
    e[r * WIDm + j] = acc;
}

// ------- prep B: pre-fragment weights into 32x32x16 MFMA A-fragment order (bf16) ----
// A-frag mapping (32x32x16): lane l holds row m=(l&31), k = 8*(l>>5)+j, j=0..7
__global__ void k_prep_frags32(const float* __restrict__ w0, const float* __restrict__ w1,
                               const float* __restrict__ w2,
                               unsigned short* __restrict__ wtab) {
    int t = blockIdx.x * 256 + threadIdx.x;
    if (t < W1F_N) {                       // w1 A-frags: tiles (mt,ks), 4x8
        int tile = t >> 9, l = (t >> 3) & 63, j = t & 7;
        int mt = tile >> 3, ks = tile & 7;
        int m = mt * 32 + (l & 31);
        int k = ks * 16 + 8 * (l >> 5) + j;
        wtab[LW1 + t] = f2b(w1[k * WIDm + m]);
    } else if (t < W1F_N + W0KF_N) {       // w0[27:39] A-frags: 4 mt tiles, K=16 (pad)
        int u = t - W1F_N;
        int mt = u >> 9, l = (u >> 3) & 63, j = u & 7;
        int m = mt * 32 + (l & 31);
        int k = 8 * (l >> 5) + j;
        wtab[LW0K + u] = f2b(k < K0C ? w0[(27 + k) * WIDm + m] : 0.0f);
    } else {                               // w2[:,0:3] A-frags: 8 ks tiles, M=32 (pad)
        int u = t - W1F_N - W0KF_N;
        int ks = u >> 9, l = (u >> 3) & 63, j = u & 7;
        int m = l & 31;
        int k = ks * 16 + 8 * (l >> 5) + j;
        wtab[LW2 + u] = f2b(m < 3 ? w2[k * 78 + m] : 0.0f);
    }
}

// =============== shared per-sample math (density chain + alpha + k0 out) ===========
static __device__ __forceinline__ void finish_sample(
    int sid, int s, const float* acc /*29*/, const float* __restrict__ gfd,
    const float* __restrict__ act_shift,
    float* __restrict__ alpha_ws, unsigned short* __restrict__ k0b)
{
    float z = acc[0] + gfd[0] * LAMc;
#pragma unroll
    for (int i = 0; i < 4; ++i) {
        float pa = acc[1 + 4 * i + 0], pb = acc[1 + 4 * i + 1];
        float pc = acc[1 + 4 * i + 2], pd = acc[1 + 4 * i + 3];
        float sg = 1.0f / (1.0f + expf(-pd));
        z += pa * tanhf(pb * z + pc) * sg;
    }
    float den = z + act_shift[s];
    float sp = fmaxf(den, 0.0f) + log1pf(expf(-fabsf(den)));
    alpha_ws[sid] = 1.0f - expf(-sp * VSRc);

    ushort8v lo, hi;
#pragma unroll
    for (int c = 0; c < 8; ++c) lo[c] = f2b(acc[17 + c]);
#pragma unroll
    for (int c = 0; c < 8; ++c) hi[c] = (c < 4) ? f2b(acc[17 + 8 + c]) : (unsigned short)0;
    *(ushort8v*)(k0b + (size_t)sid * 16)     = lo;
    *(ushort8v*)(k0b + (size_t)sid * 16 + 8) = hi;
}

static __device__ __forceinline__ void sample_coords(
    int sid, const float* __restrict__ rays_o, const float* __restrict__ rays_d,
    int& ix, int& iy, int& iz, float& fx, float& fy, float& fz)
{
    int r = sid >> 7;
    int s = sid & 127;
    float t = s * (1.0f / 127.0f);
    float px = fminf(fmaxf(rays_o[r * 3 + 0] + rays_d[r * 3 + 0] * t, 0.0f), 1.0f);
    float py = fminf(fmaxf(rays_o[r * 3 + 1] + rays_d[r * 3 + 1] * t, 0.0f), 1.0f);
    float pz = fminf(fmaxf(rays_o[r * 3 + 2] + rays_d[r * 3 + 2] * t, 0.0f), 1.0f);
    float gx = px * (float)(NXg - 1);
    float gy = py * (float)(NYg - 1);
    float gz = pz * (float)(NZg - 1);
    ix = min((int)gx, NXg - 2);
    iy = min((int)gy, NYg - 2);
    iz = min((int)gz, NZg - 2);
    fx = gx - (float)ix;
    fy = gy - (float)iy;
    fz = gz - (float)iz;
}

// ---------------- K1a: AoS gather (preferred) --------------------------------------
__global__ __launch_bounds__(256) void k_gather_aos(
    const float* __restrict__ rays_o, const float* __restrict__ rays_d,
    const unsigned short* __restrict__ vox,
    const float* __restrict__ gfd, const float* __restrict__ act_shift,
    float* __restrict__ alpha_ws, unsigned short* __restrict__ k0b)
{
    int sid = blockIdx.x * 256 + threadIdx.x;
    if (sid >= RD) return;
    int ix, iy, iz; float fx, fy, fz;
    sample_coords(sid, rays_o, rays_d, ix, iy, iz, fx, fy, fz);

    const unsigned short* base = vox + ((size_t)(ix * NYg + iy) * NZg + iz) * 32;
    const size_t qoff[4] = { 0, (size_t)NZg * 32, (size_t)NYg * NZg * 32,
                             (size_t)(NYg + 1) * NZg * 32 };
    float wxy[4];
    wxy[0] = (1.0f - fx) * (1.0f - fy);
    wxy[1] = (1.0f - fx) * fy;
    wxy[2] = fx * (1.0f - fy);
    wxy[3] = fx * fy;
    float wz0 = 1.0f - fz, wz1 = fz;

    float acc[29];
#pragma unroll
    for (int c = 0; c < 29; ++c) acc[c] = 0.0f;

#pragma unroll
    for (int q = 0; q < 4; ++q) {
        const unsigned short* p = base + qoff[q];
#pragma unroll
        for (int dz = 0; dz < 2; ++dz) {
            float w = wxy[q] * (dz ? wz1 : wz0);
            const ushort8v* pv = (const ushort8v*)(p + dz * 32);
            ushort8v v0 = pv[0], v1 = pv[1], v2 = pv[2], v3 = pv[3];
#pragma unroll
            for (int i = 0; i < 8; ++i) acc[i]      = fmaf(w, b2f(v0[i]), acc[i]);
#pragma unroll
            for (int i = 0; i < 8; ++i) acc[8 + i]  = fmaf(w, b2f(v1[i]), acc[8 + i]);
#pragma unroll
            for (int i = 0; i < 8; ++i) acc[16 + i] = fmaf(w, b2f(v2[i]), acc[16 + i]);
#pragma unroll
            for (int i = 0; i < 5; ++i) acc[24 + i] = fmaf(w, b2f(v3[i]), acc[24 + i]);
        }
    }
    finish_sample(sid, sid & 127, acc, gfd, act_shift, alpha_ws, k0b);
}

// ---------------- K1b: SoA f32 gather (fallback when ws too small) -----------------
__global__ void k_gather_soa(
    const float* __restrict__ rays_o, const float* __restrict__ rays_d,
    const float* __restrict__ dg,  const float* __restrict__ pg,
    const float* __restrict__ kg,  const float* __restrict__ gfd,
    const float* __restrict__ act_shift,
    float* __restrict__ alpha_ws, unsigned short* __restrict__ k0b)
{
    int sid = blockIdx.x * 256 + threadIdx.x;
    if (sid >= RD) return;
    int ix, iy, iz; float fx, fy, fz;
    sample_coords(sid, rays_o, rays_d, ix, iy, iz, fx, fy, fz);

    int base = (ix * NYg + iy) * NZg + iz;
    int off[4] = { base, base + NZg, base + NYg * NZg, base + NYg * NZg + NZg };
    float wxy[4];
    wxy[0] = (1.0f - fx) * (1.0f - fy);
    wxy[1] = (1.0f - fx) * fy;
    wxy[2] = fx * (1.0f - fy);
    wxy[3] = fx * fy;
    float wz0 = 1.0f - fz, wz1 = fz;

    auto tri = [&](const float* __restrict__ g, int c) -> float {
        float a = 0.0f;
        const float* gc = g + (size_t)c * CSg;
#pragma unroll
        for (int q = 0; q < 4; ++q) {
            const float* p = gc + off[q];
            a += (p[0] * wz0 + p[1] * wz1) * wxy[q];
        }
        return a;
    };
    float acc[29];
    acc[0] = tri(dg, 0);
#pragma unroll
    for (int c = 0; c < 16; ++c) acc[1 + c] = tri(pg, c);
#pragma unroll
    for (int c = 0; c < K0C; ++c) acc[17 + c] = tri(kg, c);
    finish_sample(sid, sid & 127, acc, gfd, act_shift, alpha_ws, k0b);
}

// ---------------- K2: MFMA MLP, 32x32x16, in-register permlane transpose -----------
// C/D layout (32x32): col = lane&31, row = (r&3) + 8*(r>>2) + 4*(lane>>5)  [m74/m101]
// A/B layout: row/col = lane&31, k = 8*(lane>>5) + j
struct BPair { int4v lo, hi; };

static __device__ __forceinline__ BPair ttile(const f32x16 v) {
    unsigned p[8];
#pragma unroll
    for (int q = 0; q < 8; ++q) p[q] = pk2(v[2 * q], v[2 * q + 1]);
    int2v a = __builtin_amdgcn_permlane32_swap((int)p[0], (int)p[2], false, false);
    int2v b = __builtin_amdgcn_permlane32_swap((int)p[1], (int)p[3], false, false);
    int2v c = __builtin_amdgcn_permlane32_swap((int)p[4], (int)p[6], false, false);
    int2v d = __builtin_amdgcn_permlane32_swap((int)p[5], (int)p[7], false, false);
    BPair r;
    r.lo = int4v{ a.x, b.x, a.y, b.y };   // B-frag for k-step 2*mt
    r.hi = int4v{ c.x, d.x, c.y, d.y };   // B-frag for k-step 2*mt+1
    return r;
}

__global__ __launch_bounds__(256) void k_mlp32(
    const unsigned short* __restrict__ k0b, const float* __restrict__ e,
    const unsigned short* __restrict__ wtab,
    const float* __restrict__ b1, const float* __restrict__ b2,
    const float* __restrict__ gfr,
    float* __restrict__ rgb_ws)
{
    __shared__ unsigned short wlds[WTAB_N];      // 45056 B, staged once per block
#pragma unroll
    for (int it = 0; it < WTAB_N / (256 * 8); ++it) {
        int i = (it * 256 + threadIdx.x) * 8;
        *(ushort8v*)&wlds[i] = *(const ushort8v*)&wtab[i];
    }
    __syncthreads();

    const int lane = threadIdx.x & 63;
    const int wid  = threadIdx.x >> 6;
    const int n    = lane & 31;
    const int h    = lane >> 5;
    const int sbase = blockIdx.x * 128 + wid * 32;   // one ray per block
    const int sid   = sbase + n;
    const int ray   = blockIdx.x;

    // ---- layer 0: C-init = e[ray][.] (contains emb@w0[0:27]+b0), A = w0k, B = k0 --
    f32x16 acc0[4];
#pragma unroll
    for (int mt = 0; mt < 4; ++mt) {
        const f32x4* ep = (const f32x4*)(e + (size_t)ray * WIDm + mt * 32 + 4 * h);
#pragma unroll
        for (int rr = 0; rr < 4; ++rr) {
            f32x4 ev = ep[2 * rr];
#pragma unroll
            for (int q = 0; q < 4; ++q) acc0[mt][rr * 4 + q] = ev[q];
        }
    }
    short8v bk = *(const short8v*)(k0b + (size_t)sid * 16 + h * 8);
#pragma unroll
    for (int mt = 0; mt < 4; ++mt) {
        short8v af = *(const short8v*)&wlds[LW0K + (mt * 64 + lane) * 8];
        acc0[mt] = __builtin_amdgcn_mfma_f32_32x32x16_bf16(af, bk, acc0[mt], 0, 0, 0);
    }
    // relu + in-register transpose -> B-frags for layer 1
    int4v bw[8];
#pragma unroll
    for (int mt = 0; mt < 4; ++mt) {
        f32x16 hv;
#pragma unroll
        for (int r = 0; r < 16; ++r) hv[r] = fmaxf(acc0[mt][r], 0.0f);
        BPair t = ttile(hv);
        bw[2 * mt]     = t.lo;
        bw[2 * mt + 1] = t.hi;
    }

    // ---- layer 1: C-init = b1, A = w1 frags, B = bw ----
    f32x16 acc1[4];
#pragma unroll
    for (int mt = 0; mt < 4; ++mt) {
        const f32x4* bp = (const f32x4*)(b1 + mt * 32 + 4 * h);
#pragma unroll
        for (int rr = 0; rr < 4; ++rr) {
            f32x4 bv = bp[2 * rr];
#pragma unroll
            for (int q = 0; q < 4; ++q) acc1[mt][rr * 4 + q] = bv[q];
        }
    }
#pragma unroll
    for (int mt = 0; mt < 4; ++mt)
#pragma unroll
        for (int ks = 0; ks < 8; ++ks) {
            short8v af = *(const short8v*)&wlds[LW1 + ((mt * 8 + ks) * 64 + lane) * 8];
            acc1[mt] = __builtin_amdgcn_mfma_f32_32x32x16_bf16(af, as_s8(bw[ks]), acc1[mt], 0, 0, 0);
        }
    // relu + transpose -> B-frags for layer 2
    int4v cw[8];
#pragma unroll
    for (int mt = 0; mt < 4; ++mt) {
        f32x16 hv;
#pragma unroll
        for (int r = 0; r < 16; ++r) hv[r] = fmaxf(acc1[mt][r], 0.0f);
        BPair t = ttile(hv);
        cw[2 * mt]     = t.lo;
        cw[2 * mt + 1] = t.hi;
    }

    // ---- layer 2: rgb rows 0..2 ----
    f32x16 acc2;
#pragma unroll
    for (int r = 0; r < 16; ++r) acc2[r] = 0.0f;
#pragma unroll
    for (int ks = 0; ks < 8; ++ks) {
        short8v af = *(const short8v*)&wlds[LW2 + (ks * 64 + lane) * 8];
        acc2 = __builtin_amdgcn_mfma_f32_32x32x16_bf16(af, as_s8(cw[ks]), acc2, 0, 0, 0);
    }
    if (h == 0) {   // rows 0..2 live in regs 0..2 of lanes 0..31
#pragma unroll
        for (int c = 0; c < 3; ++c) {
            float v = acc2[c] + b2[c] + gfr[c] * LAMc;
            rgb_ws[(size_t)c * RD + sid] = 1.0f / (1.0f + expf(-v));
        }
    }
}

// ---------------- K3: per-ray transmittance scan + weighted RGB reduce -------------
__global__ void k_scan_reduce(const float* __restrict__ alpha_ws,
                              const float* __restrict__ rgb_ws,
                              float* __restrict__ out)
{
    int gtid = blockIdx.x * 256 + threadIdx.x;
    int r = gtid >> 6;
    int lane = gtid & 63;
    if (r >= R_) return;

    int base = r * D_ + lane * 2;
    float a0 = alpha_ws[base];
    float a1 = alpha_ws[base + 1];
    float q0 = 1.0f - a0 + 1e-10f;
    float q1 = 1.0f - a1 + 1e-10f;
    float p = q0 * q1;

    float incl = p;
#pragma unroll
    for (int o = 1; o < 64; o <<= 1) {
        float v = __shfl_up(incl, o);
        if (lane >= o) incl *= v;
    }
    float excl = __shfl_up(incl, 1);
    if (lane == 0) excl = 1.0f;
    float Tlast = __shfl(incl, 63);

    float w0s = a0 * excl;
    float w1s = a1 * excl * q0;

    float sums[3];
#pragma unroll
    for (int c = 0; c < 3; ++c) {
        float rg0 = rgb_ws[(size_t)c * RD + base];
        float rg1 = rgb_ws[(size_t)c * RD + base + 1];
        float sc = w0s * rg0 + w1s * rg1;
#pragma unroll
        for (int o = 32; o >= 1; o >>= 1) sc += __shfl_xor(sc, o);
        sums[c] = sc;
    }
    if (lane == 0) {
#pragma unroll
        for (int c = 0; c < 3; ++c) out[r * 3 + c] = sums[c] + Tlast;
    }
}

extern "C" void kernel_launch(void* const* d_in, const int* in_sizes, int n_in,
                              void* d_out, int out_size, void* d_ws, size_t ws_size,
                              hipStream_t stream) {
    const float* rays_o    = (const float*)d_in[0];
    const float* rays_d    = (const float*)d_in[1];
    const float* dg        = (const float*)d_in[2];
    const float* pg        = (const float*)d_in[3];
    const float* kg        = (const float*)d_in[4];
    const float* gfd       = (const float*)d_in[5];
    const float* gfr       = (const float*)d_in[6];
    const float* w0        = (const float*)d_in[7];
    const float* b0        = (const float*)d_in[8];
    const float* w1        = (const float*)d_in[9];
    const float* b1        = (const float*)d_in[10];
    const float* w2        = (const float*)d_in[11];
    const float* b2        = (const float*)d_in[12];
    const float* act_shift = (const float*)d_in[13];
    float* out = (float*)d_out;

    float* ws = (float*)d_ws;
    float*          alpha_ws = ws;                               // RD f32
    float*          rgb_ws   = ws + (size_t)RD;                  // 3*RD f32
    unsigned short* k0b      = (unsigned short*)(ws + 4 * (size_t)RD);   // RD*16 u16
    float*          e_ws     = ws + 12 * (size_t)RD;             // RD f32
    unsigned short* wtab     = (unsigned short*)(ws + 13 * (size_t)RD);  // 22528 u16
    size_t frag_end = 13 * (size_t)RD * 4 + (size_t)WTAB_N * 2;
    size_t vox_off  = (frag_end + 63) & ~(size_t)63;
    unsigned short* vox = (unsigned short*)((char*)d_ws + vox_off);
    size_t need = vox_off + (size_t)CSg * 64;
    bool use_aos = (ws_size >= need);

    k_prep_e<<<dim3(R_), dim3(WIDm), 0, stream>>>(rays_d, w0, b0, e_ws);
    k_prep_frags32<<<dim3(WTAB_N / 256), dim3(256), 0, stream>>>(w0, w1, w2, wtab);
    if (use_aos) {
        k_pack_t<<<dim3(CSg / 1024), dim3(256), 0, stream>>>(dg, pg, kg, vox);
        k_gather_aos<<<dim3(RD / 256), dim3(256), 0, stream>>>(
            rays_o, rays_d, vox, gfd, act_shift, alpha_ws, k0b);
    } else {
        k_gather_soa<<<dim3(RD / 256), dim3(256), 0, stream>>>(
            rays_o, rays_d, dg, pg, kg, gfd, act_shift, alpha_ws, k0b);
    }
    k_mlp32<<<dim3(R_), dim3(256), 0, stream>>>(
        k0b, e_ws, wtab, b1, b2, gfr, rgb_ws);
    k_scan_reduce<<<dim3(R_ / 4), dim3(256), 0, stream>>>(alpha_ws, rgb_ws, out);
}